// Round 8
// baseline (517.326 us; speedup 1.0000x reference)
//
#include <hip/hip_runtime.h>
#include <hip/hip_bf16.h>

#define BB 32
#define TT 2048
#define MELS 80
#define HH 128
#define WW 64
#define DD 128

using bf16x8 = __attribute__((ext_vector_type(8))) short;
using f32x16 = __attribute__((ext_vector_type(16))) float;
using u16x4  = __attribute__((ext_vector_type(4))) ushort;

#define MFMA(av, bv, acc) acc = __builtin_amdgcn_mfma_f32_32x32x16_bf16(av, bv, acc, 0, 0, 0)

__device__ __forceinline__ ushort bf16b(float f) {
  __hip_bfloat16 h = __float2bfloat16(f);
  return *(ushort*)&h;
}

// async global->LDS 16B DMA (linear LDS dest; swizzle goes on the SOURCE)
__device__ __forceinline__ void g2l16(const ushort* g, ushort* l) {
  __builtin_amdgcn_global_load_lds((const __attribute__((address_space(1))) void*)g,
                                   (__attribute__((address_space(3))) void*)l, 16, 0, 0);
}

// Epilogue helper: scatter one 32x32 C-tile into LDS s_y[col][row] (bf16,
// 4-bit XOR swizzle on 16B blocks) with bias+optional relu.
__device__ __forceinline__ void dump_tile(const f32x16& a, int tl, int mb, int half,
                                          const float* __restrict__ bias, bool relu,
                                          ushort* s_y) {
  #pragma unroll
  for (int q = 0; q < 4; ++q) {
    int ho0 = mb + 8 * q + 4 * half;
    u16x4 p;
    #pragma unroll
    for (int j = 0; j < 4; ++j) {
      float v = a[q * 4 + j] + bias[ho0 + j];
      if (relu) v = fmaxf(v, 0.f);
      p[j] = bf16b(v);
    }
    *(u16x4*)&s_y[tl * 128 + (((ho0 >> 3) ^ (tl & 15)) << 3) + (ho0 & 7)] = p;
  }
}

// ---------------- features [b][80][t] f32 -> ft [b][t][128] bf16 (c>=80 -> 0)
__global__ __launch_bounds__(256) void tr_feat(const float* __restrict__ f,
                                               ushort* __restrict__ ft) {
  __shared__ float s[MELS][65];
  const int b = blockIdx.x >> 5, t0 = (blockIdx.x & 31) * 64;
  const int tid = threadIdx.x;
  for (int i = tid; i < MELS * 64; i += 256) {
    int c = i >> 6, t = i & 63;
    s[c][t] = f[(b * MELS + c) * TT + t0 + t];
  }
  __syncthreads();
  for (int i = tid; i < 64 * 128; i += 256) {
    int t = i >> 7, c = i & 127;
    float v = (c < MELS) ? s[c][t] : 0.f;
    ft[(b * TT + t0 + t) * 128 + c] = bf16b(v);
  }
}

// ---------------- weight repacks to MFMA A-frag order ----------------------
template<int NSS>
__global__ __launch_bounds__(256) void repack1d(const float* __restrict__ w,
                                                ushort* __restrict__ Wb) {
  int i = blockIdx.x * 256 + threadIdx.x;   // 5*NSS*2048 exact
  int e = i & 7, m = (i >> 3) & 127, half = (i >> 10) & 1;
  int r = i >> 11;
  int ss = r % NSS, kw = r / NSS;
  int c = ss * 16 + half * 8 + e;
  const int C = (NSS == 5) ? MELS : HH;
  Wb[i] = bf16b(w[(m * C + c) * 5 + kw]);
}
__global__ __launch_bounds__(256) void repack2d(const float* __restrict__ cw,
                                                ushort* __restrict__ Wc) {
  int i = blockIdx.x * 256 + threadIdx.x;   // 409600 exact
  int e = i & 7, m = (i >> 3) & 127, half = (i >> 10) & 1, ss = (i >> 11) & 7;
  int r = i >> 14;
  int kw = r % 5, kd = r / 5;
  int hi = ss * 16 + half * 8 + e;
  Wc[i] = bf16b(cw[((m * HH + hi) * 5 + kw) * 5 + kd]);
}

// ---------------- prep: tail constants for conv2d2 -------------------------
// T2[(ho*5+kw)*3 + v]: v=0 sum kd 0..4; v=1 kd 0..3; v=2 kd 0..2 (for d=126,127)
// Ls[c] = sum_{d>=c*32} lw[d]
__global__ __launch_bounds__(256) void prep_k(const float* __restrict__ cw2,
                                              const float* __restrict__ cb1,
                                              const float* __restrict__ lw,
                                              float* __restrict__ T2,
                                              float* __restrict__ Ls) {
  int i = blockIdx.x * 256 + threadIdx.x;
  if (i < 640) {
    int ho = i / 5, kw = i - ho * 5;
    float sA = 0.f, sB = 0.f, sC = 0.f;
    for (int hi = 0; hi < HH; ++hi) {
      float yc = fmaxf(cb1[hi], 0.f);
      const float* p = cw2 + ((ho * HH + hi) * 5 + kw) * 5;
      float c012 = p[0] + p[1] + p[2];
      sC += c012 * yc;
      sB += (c012 + p[3]) * yc;
      sA += (c012 + p[3] + p[4]) * yc;
    }
    T2[i * 3 + 0] = sA; T2[i * 3 + 1] = sB; T2[i * 3 + 2] = sC;
  } else if (i < 645) {
    int c = i - 640;
    float s = 0.f;
    for (int d = c * 32; d < 128; ++d) s += lw[d];
    Ls[c] = s;   // Ls[4] = 0
  }
}

// ---------------- conv1d via MFMA: xt[b][t][128] -> yt[b][t][128] ----------
template<int NSS, int RELU>
__global__ __launch_bounds__(256) void conv1d_mfma(
    const ushort* __restrict__ xt, const ushort* __restrict__ Wb,
    const float* __restrict__ bias, ushort* __restrict__ yt,
    const ushort* __restrict__ zp) {
  __shared__ __align__(16) ushort s_x[2112 * 8];
  const int bid = blockIdx.x;
  const int nid = (bid & 7) * 64 + (bid >> 3);   // XCD-chunked (512 % 8 == 0)
  const int b = nid >> 4;
  const int t0 = (nid & 15) << 7;
  const int tid = threadIdx.x;
  const int lane = tid & 63, wv = tid >> 6;
  const int l31 = lane & 31, half = lane >> 5;
  const int m_w = (wv >> 1) * 64, n_w = (wv & 1) * 64;

  #pragma unroll
  for (int it = 0; it < 9; ++it) {
    int slot = it * 256 + tid;
    if (slot < 2112) {
      int row = slot >> 4, bsw = (slot & 15) ^ (row & 15);
      int t = t0 + row - 2;
      const ushort* src = (t >= 0 && t < TT)
          ? xt + (((size_t)(b * TT + t)) << 7) + bsw * 8 : zp;
      g2l16(src, s_x + slot * 8);
    }
  }
  __syncthreads();

  f32x16 a00 = 0.f, a01 = 0.f, a10 = 0.f, a11 = 0.f;
  const bf16x8* Ap = (const bf16x8*)Wb;
  constexpr int G = 5 * NSS;
  bf16x8 ar[3][2];
  #pragma unroll
  for (int p = 0; p < 2; ++p) {
    ar[p][0] = Ap[(p * 2 + half) * 128 + m_w + l31];
    ar[p][1] = Ap[(p * 2 + half) * 128 + m_w + l31 + 32];
  }
  __builtin_amdgcn_sched_barrier(0);
  #pragma unroll
  for (int g = 0; g < G; ++g) {
    if (g + 2 < G) {
      ar[(g + 2) % 3][0] = Ap[((g + 2) * 2 + half) * 128 + m_w + l31];
      ar[(g + 2) % 3][1] = Ap[((g + 2) * 2 + half) * 128 + m_w + l31 + 32];
      __builtin_amdgcn_sched_barrier(0);
    }
    const int kw = g / NSS, ss = g % NSS;
    int r0 = n_w + l31 + kw, r1 = r0 + 32;
    int blk = ss * 2 + half;
    bf16x8 bv0 = *(const bf16x8*)&s_x[r0 * 128 + ((blk ^ (r0 & 15)) << 3)];
    bf16x8 bv1 = *(const bf16x8*)&s_x[r1 * 128 + ((blk ^ (r1 & 15)) << 3)];
    bf16x8 av0 = ar[g % 3][0], av1 = ar[g % 3][1];
    MFMA(av0, bv0, a00); MFMA(av0, bv1, a01);
    MFMA(av1, bv0, a10); MFMA(av1, bv1, a11);
  }
  __syncthreads();
  dump_tile(a00, n_w + l31,      m_w,      half, bias, RELU != 0, s_x);
  dump_tile(a01, n_w + 32 + l31, m_w,      half, bias, RELU != 0, s_x);
  dump_tile(a10, n_w + l31,      m_w + 32, half, bias, RELU != 0, s_x);
  dump_tile(a11, n_w + 32 + l31, m_w + 32, half, bias, RELU != 0, s_x);
  __syncthreads();
  #pragma unroll
  for (int it = 0; it < 8; ++it) {
    int i = it * 256 + tid;
    int tl = i >> 4, blk = i & 15;
    bf16x8 v = *(const bf16x8*)&s_x[tl * 128 + ((blk ^ (tl & 15)) << 3)];
    *(bf16x8*)(yt + (((size_t)(b * TT + t0 + tl)) << 7) + blk * 8) = v;
  }
}

// ---- shared compute macro for conv2d: one kw slab, A-regs triple-buffered --
// (depth-2 prefetch: group g+2 issued while group g computes; sched_barrier
// pins the issue point so the scheduler cannot sink the loads to their use)
// NB = number of active 64-wide n-blocks for this wave (2 = both, 1 = bv0 only)
#define COMPUTE2D(KW, BUF, NB)                                                 \
  {                                                                            \
    bf16x8 ar[3][8];                                                           \
    _Pragma("unroll")                                                          \
    for (int p = 0; p < 2; ++p) {                                              \
      int shp = (p & 1) * 4;                                                   \
      _Pragma("unroll")                                                        \
      for (int j = 0; j < 8; ++j)                                              \
        ar[p][j] = Ap[(((0 * 5 + (KW)) * 8 + shp + (j >> 1)) * 2 + half) * 128 \
                      + m_w + l31 + (j & 1) * 32];                             \
    }                                                                          \
    __builtin_amdgcn_sched_barrier(0);                                         \
    _Pragma("unroll")                                                          \
    for (int g = 0; g < 10; ++g) {                                             \
      int kd = g >> 1, sh = (g & 1) * 4;                                       \
      if (g < 8) {                                                             \
        int kd2 = (g + 2) >> 1, sh2 = ((g + 2) & 1) * 4;                       \
        _Pragma("unroll")                                                      \
        for (int j = 0; j < 8; ++j)                                            \
          ar[(g + 2) % 3][j] = Ap[(((kd2 * 5 + (KW)) * 8 + sh2 + (j >> 1)) * 2 \
                                   + half) * 128 + m_w + l31 + (j & 1) * 32];  \
        __builtin_amdgcn_sched_barrier(0);                                     \
      }                                                                        \
      _Pragma("unroll")                                                        \
      for (int s2 = 0; s2 < 4; ++s2) {                                         \
        int ss = sh + s2;                                                      \
        int r0 = n_w + l31 + kd;                                               \
        int blk = ss * 2 + half;                                               \
        bf16x8 bv0 = *(const bf16x8*)&(BUF)[r0 * 128 + ((blk ^ (r0 & 15)) << 3)]; \
        MFMA(ar[g % 3][s2 * 2],     bv0, a00);                                 \
        MFMA(ar[g % 3][s2 * 2 + 1], bv0, a10);                                 \
        if ((NB) > 1) {                                                        \
          int r1 = r0 + 32;                                                    \
          bf16x8 bv1 = *(const bf16x8*)&(BUF)[r1 * 128 + ((blk ^ (r1 & 15)) << 3)]; \
          MFMA(ar[g % 3][s2 * 2],     bv1, a01);                               \
          MFMA(ar[g % 3][s2 * 2 + 1], bv1, a11);                               \
        }                                                                      \
      }                                                                        \
    }                                                                          \
  }

// ---------------- fused gather + conv2d #1 (MFMA) -> y1t[b][w][d][hi] ------
__global__ __launch_bounds__(256, 2) void conv2d1_mfma(
    const ushort* __restrict__ embt, const int* __restrict__ wb,
    const int* __restrict__ wlen, const ushort* __restrict__ Wc,
    const float* __restrict__ cb, ushort* __restrict__ y1t,
    const ushort* __restrict__ zp) {
  extern __shared__ __align__(16) ushort smem[];   // 2 x 16896 ushorts
  const int bid = blockIdx.x;
  const int nid = (bid & 7) * 256 + (bid >> 3);    // XCD-chunked (2048 % 8 == 0)
  const int b = nid >> 6, w = nid & 63;
  const int tid = threadIdx.x;
  const int lane = tid & 63, wv = tid >> 6;
  const int l31 = lane & 31, half = lane >> 5;
  const int m_w = (wv >> 1) * 64, n_w = (wv & 1) * 64;

  int stv[5], duv[5];
  const int wl = wlen[b];
  #pragma unroll
  for (int i = 0; i < 5; ++i) {
    int wq = w + i - 2;
    bool ok = ((unsigned)wq < WW) && (wq < wl);
    int st = ok ? wb[b * 128 + wq] : 0;
    int en = ok ? wb[b * 128 + 64 + wq] : 0;
    stv[i] = st;
    duv[i] = ok ? min(en - st, 128) : 0;
  }
  // y1[w,d] is exactly relu(cb1) (const per channel) for d >= max5(dur)+2:
  // compute only the first NT1 32-wide d-tiles, const-fill the rest.
  int dcap = 0;
  #pragma unroll
  for (int i = 0; i < 5; ++i) dcap = max(dcap, duv[i]);
  const int NT1 = min(4, max(1, (dcap + 2 + 31) >> 5));
  const int rstage = min(132, NT1 * 32 + 4);
  const int t0a = n_w >> 5;
  const bool act0 = t0a < NT1, act1 = t0a + 1 < NT1;

#define STAGE1(KW, BUF)                                                        \
  {                                                                            \
    const int st_ = stv[KW], du_ = duv[KW];                                    \
    _Pragma("unroll")                                                          \
    for (int it = 0; it < 9; ++it) {                                           \
      int slot = it * 256 + tid;                                               \
      if (slot < 2112) {                                                       \
        int row = slot >> 4;                                                   \
        if (row < rstage) {                                                    \
          int bsw = (slot & 15) ^ (row & 15);                                  \
          int dq = row - 2;                                                    \
          const ushort* src = ((unsigned)dq < (unsigned)du_)                   \
              ? embt + (((size_t)(b * TT + st_ + dq)) << 7) + bsw * 8 : zp;    \
          g2l16(src, (BUF) + slot * 8);                                        \
        }                                                                      \
      }                                                                        \
    }                                                                          \
  }

  STAGE1(0, smem);
  __syncthreads();

  f32x16 a00 = 0.f, a01 = 0.f, a10 = 0.f, a11 = 0.f;
  const bf16x8* Ap = (const bf16x8*)Wc;

  #pragma unroll
  for (int kw = 0; kw < 5; ++kw) {
    ushort* cur = smem + (kw & 1) * 16896;
    if (kw < 4) {
      ushort* nxt = smem + ((kw + 1) & 1) * 16896;
      switch (kw + 1) {     // compile-time under unroll
        case 1: STAGE1(1, nxt); break;
        case 2: STAGE1(2, nxt); break;
        case 3: STAGE1(3, nxt); break;
        case 4: STAGE1(4, nxt); break;
      }
    }
    if (act1)      { COMPUTE2D(kw, cur, 2); }
    else if (act0) { COMPUTE2D(kw, cur, 1); }
    __syncthreads();
  }
#undef STAGE1

  if (act0) {
    dump_tile(a00, n_w + l31, m_w,      half, cb, true, smem);
    dump_tile(a10, n_w + l31, m_w + 32, half, cb, true, smem);
  }
  if (act1) {
    dump_tile(a01, n_w + 32 + l31, m_w,      half, cb, true, smem);
    dump_tile(a11, n_w + 32 + l31, m_w + 32, half, cb, true, smem);
  }
  __syncthreads();
  // const vector for d >= NT1*32 (this thread's fixed 8 channels)
  bf16x8 cv;
  {
    int blkc = tid & 15;
    #pragma unroll
    for (int j = 0; j < 8; ++j)
      ((ushort*)&cv)[j] = bf16b(fmaxf(cb[blkc * 8 + j], 0.f));
  }
  #pragma unroll
  for (int it = 0; it < 8; ++it) {
    int i = it * 256 + tid;
    int d = i >> 4, blk = i & 15;
    bf16x8 v = (d < NT1 * 32)
        ? *(const bf16x8*)&smem[d * 128 + ((blk ^ (d & 15)) << 3)] : cv;
    *(bf16x8*)(y1t + (((size_t)(b * WW + w) * DD + d) << 7) + blk * 8) = v;
  }
}

// ---------------- conv2d #2 (MFMA) + relu + einsum(lw) + relu -> z f32 -----
__global__ __launch_bounds__(256, 2) void conv2d2_mfma(
    const ushort* __restrict__ y1t, const int* __restrict__ wb,
    const int* __restrict__ wlen, const ushort* __restrict__ Wc,
    const float* __restrict__ cb, const float* __restrict__ lw,
    const float* __restrict__ lb, const float* __restrict__ T2,
    const float* __restrict__ Ls, float* __restrict__ z,
    const ushort* __restrict__ zp) {
  extern __shared__ __align__(16) ushort smem[];   // 2 x 16896 ushorts
  const int bid = blockIdx.x;
  const int nid = (bid & 7) * 256 + (bid >> 3);
  const int b = nid >> 6, w = nid & 63;
  const int tid = threadIdx.x;
  const int lane = tid & 63, wv = tid >> 6;
  const int l31 = lane & 31, half = lane >> 5;
  const int m_w = (wv >> 1) * 64, n_w = (wv & 1) * 64;

  // y2[w,d] is analytically const for d >= max over w±4 (9 words) of dur + 4
  // (y1[wq] is const only for dq >= max over wq±2 of dur + 2, wq spans w±2)
  int dmax = 0;
  const int wl = wlen[b];
  #pragma unroll
  for (int i = 0; i < 9; ++i) {
    int wq = w + i - 4;
    if ((unsigned)wq < WW && wq < wl) {
      int du = min(wb[b * 128 + 64 + wq] - wb[b * 128 + wq], 128);
      dmax = max(dmax, du);
    }
  }
  const int NT2 = min(4, max(1, (dmax + 4 + 31) >> 5));
  const int rstage = min(132, NT2 * 32 + 4);
  const int t0a = n_w >> 5;
  const bool act0 = t0a < NT2, act1 = t0a + 1 < NT2;

#define STAGE2(KW, BUF)                                                        \
  {                                                                            \
    const int wq_ = w + (KW) - 2;                                              \
    const bool wok_ = (unsigned)wq_ < WW;                                      \
    _Pragma("unroll")                                                          \
    for (int it = 0; it < 9; ++it) {                                           \
      int slot = it * 256 + tid;                                               \
      if (slot < 2112) {                                                       \
        int row = slot >> 4;                                                   \
        if (row < rstage) {                                                    \
          int bsw = (slot & 15) ^ (row & 15);                                  \
          int dq = row - 2;                                                    \
          const ushort* src = (wok_ && (unsigned)dq < (unsigned)DD)            \
              ? y1t + (((size_t)(b * WW + wq_) * DD + dq) << 7) + bsw * 8 : zp;\
          g2l16(src, (BUF) + slot * 8);                                        \
        }                                                                      \
      }                                                                        \
    }                                                                          \
  }

  STAGE2(0, smem);
  __syncthreads();

  f32x16 a00 = 0.f, a01 = 0.f, a10 = 0.f, a11 = 0.f;
  const bf16x8* Ap = (const bf16x8*)Wc;

  #pragma unroll
  for (int kw = 0; kw < 5; ++kw) {
    ushort* cur = smem + (kw & 1) * 16896;
    if (kw < 4) {
      ushort* nxt = smem + ((kw + 1) & 1) * 16896;
      switch (kw + 1) {
        case 1: STAGE2(1, nxt); break;
        case 2: STAGE2(2, nxt); break;
        case 3: STAGE2(3, nxt); break;
        case 4: STAGE2(4, nxt); break;
      }
    }
    if (act1)      { COMPUTE2D(kw, cur, 2); }
    else if (act0) { COMPUTE2D(kw, cur, 1); }
    __syncthreads();
  }
#undef STAGE2

  // epilogue: relu(acc+cb)*lw over computed d, reduce; const tail analytic
  float* s_red = (float*)smem;            // [128][2]
  const float lw0 = lw[n_w + l31], lw1 = lw[n_w + 32 + l31];
  #pragma unroll
  for (int r = 0; r < 16; ++r) {
    int rowoff = (r & 3) + 8 * (r >> 2) + 4 * half;
    {
      int ho = m_w + rowoff;
      float c = cb[ho];
      float v = (act0 ? fmaxf(a00[r] + c, 0.f) * lw0 : 0.f)
              + (act1 ? fmaxf(a01[r] + c, 0.f) * lw1 : 0.f);
      v += __shfl_xor(v, 1); v += __shfl_xor(v, 2); v += __shfl_xor(v, 4);
      v += __shfl_xor(v, 8); v += __shfl_xor(v, 16);
      if (l31 == 0) s_red[ho * 2 + (wv & 1)] = v;
    }
    {
      int ho = m_w + 32 + rowoff;
      float c = cb[ho];
      float v = (act0 ? fmaxf(a10[r] + c, 0.f) * lw0 : 0.f)
              + (act1 ? fmaxf(a11[r] + c, 0.f) * lw1 : 0.f);
      v += __shfl_xor(v, 1); v += __shfl_xor(v, 2); v += __shfl_xor(v, 4);
      v += __shfl_xor(v, 8); v += __shfl_xor(v, 16);
      if (l31 == 0) s_red[ho * 2 + (wv & 1)] = v;
    }
  }
  __syncthreads();
  if (tid < HH) {
    int ho = tid;
    float hiv = 0.f;
    if (NT2 < 4) {
      float ccA = 0.f, ccB = 0.f, ccC = 0.f;
      #pragma unroll
      for (int kw = 0; kw < 5; ++kw) {
        int wq = w + kw - 2;
        if ((unsigned)wq < WW) {
          ccA += T2[(ho * 5 + kw) * 3 + 0];
          ccB += T2[(ho * 5 + kw) * 3 + 1];
          ccC += T2[(ho * 5 + kw) * 3 + 2];
        }
      }
      float c = cb[ho];
      float l126 = lw[126], l127 = lw[127];
      hiv = fmaxf(ccA + c, 0.f) * (Ls[NT2] - l126 - l127)
          + fmaxf(ccB + c, 0.f) * l126
          + fmaxf(ccC + c, 0.f) * l127;
    }
    float zz = fmaxf(s_red[ho * 2] + s_red[ho * 2 + 1] + hiv + lb[0], 0.f);
    z[(b * HH + ho) * WW + w] = zz;
  }
}

// ---------------- final conv2d (1 out channel, D-dim=1 -> only kd=2) -------
__global__ __launch_bounds__(64) void final_k(const float* __restrict__ z,
        const float* __restrict__ cw3, const float* __restrict__ cb3,
        float* __restrict__ out) {
  const int b = blockIdx.x;
  const int w = threadIdx.x;
  float acc = cb3[0];
  for (int hi = 0; hi < HH; ++hi) {
    const float* zp = z + (b * HH + hi) * WW;
    #pragma unroll
    for (int kw = 0; kw < 5; ++kw) {
      int ww = w + kw - 2;
      if (ww >= 0 && ww < WW) acc += cw3[hi * 25 + kw * 5 + 2] * zp[ww];
    }
  }
  out[b * WW + w] = acc;
}

extern "C" void kernel_launch(void* const* d_in, const int* in_sizes, int n_in,
                              void* d_out, int out_size, void* d_ws, size_t ws_size,
                              hipStream_t stream) {
  const float* features = (const float*)d_in[0];
  const int*   wbnd     = (const int*)d_in[1];
  const int*   wlen     = (const int*)d_in[2];
  const float* w1  = (const float*)d_in[3];
  const float* b1  = (const float*)d_in[4];
  const float* w2  = (const float*)d_in[5];
  const float* b2  = (const float*)d_in[6];
  const float* w3  = (const float*)d_in[7];
  const float* b3  = (const float*)d_in[8];
  const float* cw1 = (const float*)d_in[9];
  const float* cb1 = (const float*)d_in[10];
  const float* cw2 = (const float*)d_in[11];
  const float* cb2 = (const float*)d_in[12];
  const float* lw  = (const float*)d_in[13];
  const float* lb  = (const float*)d_in[14];
  const float* cw3 = (const float*)d_in[15];
  const float* cb3 = (const float*)d_in[16];
  float* out = (float*)d_out;

  char* ws = (char*)d_ws;
  ushort* ft   = (ushort*)(ws + 0);           // 16,777,216 B  [b][t][128]
  ushort* x1t  = (ushort*)(ws + 16777216);
  ushort* x2t  = (ushort*)(ws + 33554432);
  ushort* embt = (ushort*)(ws + 0);           // over ft (dead after layer1)
  ushort* y1t  = (ushort*)(ws + 16777216);    // 67,108,864 B (x1t/x2t dead)
  float*  z    = (float*)(ws + 83886080);     // 1,048,576 B
  ushort* Wb1  = (ushort*)(ws + 84934656);    // 102,400 B
  ushort* Wb2  = (ushort*)(ws + 85037056);    // 163,840 B
  ushort* Wb3  = (ushort*)(ws + 85200896);    // 163,840 B
  ushort* Wc1  = (ushort*)(ws + 85364736);    // 819,200 B
  ushort* Wc2  = (ushort*)(ws + 86183936);    // 819,200 B
  ushort* zp   = (ushort*)(ws + 87003136);    // 4,096 B zero page
  float*  T2   = (float*)(ws + 87007232);     // 7,680 B (640*3 f32)
  float*  Ls   = (float*)(ws + 87014912);     // 20 B

  hipMemsetAsync(zp, 0, 4096, stream);

  const int DYN = 2 * 16896 * 2;              // 67,584 B dynamic LDS
  hipFuncSetAttribute((const void*)conv2d1_mfma,
                      hipFuncAttributeMaxDynamicSharedMemorySize, DYN);
  hipFuncSetAttribute((const void*)conv2d2_mfma,
                      hipFuncAttributeMaxDynamicSharedMemorySize, DYN);

  tr_feat<<<1024, 256, 0, stream>>>(features, ft);
  repack1d<5><<<200, 256, 0, stream>>>(w1, Wb1);
  repack1d<8><<<320, 256, 0, stream>>>(w2, Wb2);
  repack1d<8><<<320, 256, 0, stream>>>(w3, Wb3);
  repack2d<<<1600, 256, 0, stream>>>(cw1, Wc1);
  repack2d<<<1600, 256, 0, stream>>>(cw2, Wc2);
  prep_k<<<3, 256, 0, stream>>>(cw2, cb1, lw, T2, Ls);
  conv1d_mfma<5, 1><<<512, 256, 0, stream>>>(ft, Wb1, b1, x1t, zp);
  conv1d_mfma<8, 1><<<512, 256, 0, stream>>>(x1t, Wb2, b2, x2t, zp);
  conv1d_mfma<8, 0><<<512, 256, 0, stream>>>(x2t, Wb3, b3, embt, zp);
  conv2d1_mfma<<<BB * WW, 256, DYN, stream>>>(embt, wbnd, wlen, Wc1, cb1, y1t, zp);
  conv2d2_mfma<<<BB * WW, 256, DYN, stream>>>(y1t, wbnd, wlen, Wc2, cb2, lw, lb,
                                              T2, Ls, z, zp);
  final_k<<<BB, 64, 0, stream>>>(z, cw3, cb3, out);
}

// Round 9
// 435.070 us; speedup vs baseline: 1.1891x; 1.1891x over previous
//
#include <hip/hip_runtime.h>
#include <hip/hip_bf16.h>

#define BB 32
#define TT 2048
#define MELS 80
#define HH 128
#define WW 64
#define DD 128

using bf16x8 = __attribute__((ext_vector_type(8))) short;
using f32x16 = __attribute__((ext_vector_type(16))) float;
using u16x4  = __attribute__((ext_vector_type(4))) ushort;

#define MFMA(av, bv, acc) acc = __builtin_amdgcn_mfma_f32_32x32x16_bf16(av, bv, acc, 0, 0, 0)

__device__ __forceinline__ ushort bf16b(float f) {
  __hip_bfloat16 h = __float2bfloat16(f);
  return *(ushort*)&h;
}

// async global->LDS 16B DMA (linear LDS dest; swizzle goes on the SOURCE)
__device__ __forceinline__ void g2l16(const ushort* g, ushort* l) {
  __builtin_amdgcn_global_load_lds((const __attribute__((address_space(1))) void*)g,
                                   (__attribute__((address_space(3))) void*)l, 16, 0, 0);
}

// Epilogue helper: scatter one 32x32 C-tile into LDS s_y[col][row] (bf16,
// 4-bit XOR swizzle on 16B blocks) with bias+optional relu.
__device__ __forceinline__ void dump_tile(const f32x16& a, int tl, int mb, int half,
                                          const float* __restrict__ bias, bool relu,
                                          ushort* s_y) {
  #pragma unroll
  for (int q = 0; q < 4; ++q) {
    int ho0 = mb + 8 * q + 4 * half;
    u16x4 p;
    #pragma unroll
    for (int j = 0; j < 4; ++j) {
      float v = a[q * 4 + j] + bias[ho0 + j];
      if (relu) v = fmaxf(v, 0.f);
      p[j] = bf16b(v);
    }
    *(u16x4*)&s_y[tl * 128 + (((ho0 >> 3) ^ (tl & 15)) << 3) + (ho0 & 7)] = p;
  }
}

// ---------------- fused prep: tr_feat + 3x repack1d + 2x repack2d + T2/Ls + zp
__global__ __launch_bounds__(256) void prep_all(
    const float* __restrict__ features,
    const float* __restrict__ w1, const float* __restrict__ w2,
    const float* __restrict__ w3, const float* __restrict__ cw1,
    const float* __restrict__ cw2, const float* __restrict__ cb1,
    const float* __restrict__ lw,
    ushort* __restrict__ ft, ushort* __restrict__ Wb1, ushort* __restrict__ Wb2,
    ushort* __restrict__ Wb3, ushort* __restrict__ Wc1, ushort* __restrict__ Wc2,
    float* __restrict__ T2, float* __restrict__ Ls, ushort* __restrict__ zp) {
  __shared__ float s[MELS][65];
  const int bb = blockIdx.x, tid = threadIdx.x;
  if (bb < 1024) {
    // features [b][80][t] f32 -> ft [b][t][128] bf16 (c>=80 -> 0)
    const int b = bb >> 5, t0 = (bb & 31) * 64;
    for (int i = tid; i < MELS * 64; i += 256) {
      int c = i >> 6, t = i & 63;
      s[c][t] = features[(b * MELS + c) * TT + t0 + t];
    }
    __syncthreads();
    for (int i = tid; i < 64 * 128; i += 256) {
      int t = i >> 7, c = i & 127;
      float v = (c < MELS) ? s[c][t] : 0.f;
      ft[(b * TT + t0 + t) * 128 + c] = bf16b(v);
    }
  } else if (bb < 1864) {
    // repack1d: w[m][c][kw] -> Wb[kw][ss][half][m][e], c = ss*16+half*8+e
    int rel, NSS, C; const float* w; ushort* Wb;
    if (bb < 1224)      { rel = bb - 1024; NSS = 5; C = MELS; w = w1; Wb = Wb1; }
    else if (bb < 1544) { rel = bb - 1224; NSS = 8; C = HH;   w = w2; Wb = Wb2; }
    else                { rel = bb - 1544; NSS = 8; C = HH;   w = w3; Wb = Wb3; }
    int i = rel * 256 + tid;
    int e = i & 7, m = (i >> 3) & 127, half = (i >> 10) & 1;
    int r = i >> 11;
    int ss = r % NSS, kw = r / NSS;
    int c = ss * 16 + half * 8 + e;
    Wb[i] = bf16b(w[(m * C + c) * 5 + kw]);
  } else if (bb < 5064) {
    // repack2d: cw[m][hi][kw][kd] -> Wc[kd][kw][ss][half][m][e]
    int rel; const float* cw; ushort* Wc;
    if (bb < 3464) { rel = bb - 1864; cw = cw1; Wc = Wc1; }
    else           { rel = bb - 3464; cw = cw2; Wc = Wc2; }
    int i = rel * 256 + tid;
    int e = i & 7, m = (i >> 3) & 127, half = (i >> 10) & 1, ss = (i >> 11) & 7;
    int r = i >> 14;
    int kw = r % 5, kd = r / 5;
    int hi = ss * 16 + half * 8 + e;
    Wc[i] = bf16b(cw[((m * HH + hi) * 5 + kw) * 5 + kd]);
  } else if (bb < 5067) {
    // T2[(ho*5+kw)*3+v]: v=0 kd0..4; v=1 kd0..3; v=2 kd0..2.  Ls[c]=sum_{d>=32c} lw
    int i = (bb - 5064) * 256 + tid;
    if (i < 640) {
      int ho = i / 5, kw = i - ho * 5;
      float sA = 0.f, sB = 0.f, sC = 0.f;
      for (int hi = 0; hi < HH; ++hi) {
        float yc = fmaxf(cb1[hi], 0.f);
        const float* p = cw2 + ((ho * HH + hi) * 5 + kw) * 5;
        float c012 = p[0] + p[1] + p[2];
        sC += c012 * yc;
        sB += (c012 + p[3]) * yc;
        sA += (c012 + p[3] + p[4]) * yc;
      }
      T2[i * 3 + 0] = sA; T2[i * 3 + 1] = sB; T2[i * 3 + 2] = sC;
    } else if (i < 645) {
      int c = i - 640;
      float sv = 0.f;
      for (int d = c * 32; d < 128; ++d) sv += lw[d];
      Ls[c] = sv;   // Ls[4] = 0
    }
  } else {
    *(bf16x8*)(zp + tid * 8) = (short)0;   // 4096 B zero page
  }
}

// ---------------- conv1d via MFMA: xt[b][t][128] -> yt[b][t][128] ----------
// t-tile 64, grid 1024, slab 68 rows (17.4 KB) -> 4 blocks/CU, 16 waves/CU.
// waves 2x2 over (m64, n32); per wave M64xN32, acc 2x f32x16.
template<int NSS, int RELU>
__global__ __launch_bounds__(256) void conv1d_mfma(
    const ushort* __restrict__ xt, const ushort* __restrict__ Wb,
    const float* __restrict__ bias, ushort* __restrict__ yt,
    const ushort* __restrict__ zp) {
  __shared__ __align__(16) ushort s_x[1088 * 8];
  const int bid = blockIdx.x;
  const int nid = (bid & 7) * 128 + (bid >> 3);   // XCD-chunked (1024 % 8 == 0)
  const int b = nid >> 5;
  const int t0 = (nid & 31) << 6;
  const int tid = threadIdx.x;
  const int lane = tid & 63, wv = tid >> 6;
  const int l31 = lane & 31, half = lane >> 5;
  const int m_w = (wv >> 1) * 64, n32 = (wv & 1) * 32;

  #pragma unroll
  for (int it = 0; it < 5; ++it) {
    int slot = it * 256 + tid;
    if (slot < 1088) {
      int row = slot >> 4, bsw = (slot & 15) ^ (row & 15);
      int t = t0 + row - 2;
      const ushort* src = ((unsigned)t < TT)
          ? xt + (((size_t)(b * TT + t)) << 7) + bsw * 8 : zp;
      g2l16(src, s_x + slot * 8);
    }
  }
  __syncthreads();

  f32x16 a0 = 0.f, a1 = 0.f;
  const bf16x8* Ap = (const bf16x8*)Wb;
  constexpr int G = 5 * NSS;
  #pragma unroll
  for (int g = 0; g < G; ++g) {
    const int kw = g / NSS, ss = g % NSS;
    int r0 = n32 + l31 + kw;
    int blk = ss * 2 + half;
    bf16x8 bv = *(const bf16x8*)&s_x[r0 * 128 + ((blk ^ (r0 & 15)) << 3)];
    int ai = ((kw * NSS + ss) * 2 + half) * 128 + m_w + l31;
    MFMA(Ap[ai],      bv, a0);
    MFMA(Ap[ai + 32], bv, a1);
  }
  __syncthreads();
  dump_tile(a0, n32 + l31, m_w,      half, bias, RELU != 0, s_x);
  dump_tile(a1, n32 + l31, m_w + 32, half, bias, RELU != 0, s_x);
  __syncthreads();
  #pragma unroll
  for (int it = 0; it < 4; ++it) {
    int i = it * 256 + tid;        // 64 t x 16 blk = 1024 slots
    int tl = i >> 4, blk = i & 15;
    bf16x8 v = *(const bf16x8*)&s_x[tl * 128 + ((blk ^ (tl & 15)) << 3)];
    *(bf16x8*)(yt + (((size_t)(b * TT + t0 + tl)) << 7) + blk * 8) = v;
  }
}

// ---- per-wave compute of one kw slab: M64 x N64, A-regs double-buffered ----
// NB = number of active 64-wide n-blocks for this wave (2 = both, 1 = bv0 only)
#define COMPUTE2D(KW, BUF, NB)                                                 \
  {                                                                            \
    bf16x8 ar[2][8];                                                           \
    _Pragma("unroll")                                                          \
    for (int j = 0; j < 8; ++j)                                                \
      ar[0][j] = Ap[(((0 * 5 + (KW)) * 8 + (j >> 1)) * 2 + half) * 128 +       \
                    m_w + l31 + (j & 1) * 32];                                 \
    _Pragma("unroll")                                                          \
    for (int g = 0; g < 10; ++g) {                                             \
      int kd = g >> 1, sh = (g & 1) * 4;                                       \
      if (g < 9) {                                                             \
        int kd2 = (g + 1) >> 1, sh2 = ((g + 1) & 1) * 4;                       \
        _Pragma("unroll")                                                      \
        for (int j = 0; j < 8; ++j)                                            \
          ar[(g + 1) & 1][j] = Ap[(((kd2 * 5 + (KW)) * 8 + sh2 + (j >> 1)) * 2 \
                                   + half) * 128 + m_w + l31 + (j & 1) * 32];  \
      }                                                                        \
      _Pragma("unroll")                                                        \
      for (int s2 = 0; s2 < 4; ++s2) {                                         \
        int ss = sh + s2;                                                      \
        int r0 = n_w + l31 + kd;                                               \
        int blk = ss * 2 + half;                                               \
        bf16x8 bv0 = *(const bf16x8*)&(BUF)[r0 * 128 + ((blk ^ (r0 & 15)) << 3)]; \
        MFMA(ar[g & 1][s2 * 2],     bv0, a00);                                 \
        MFMA(ar[g & 1][s2 * 2 + 1], bv0, a10);                                 \
        if ((NB) > 1) {                                                        \
          int r1 = r0 + 32;                                                    \
          bf16x8 bv1 = *(const bf16x8*)&(BUF)[r1 * 128 + ((blk ^ (r1 & 15)) << 3)]; \
          MFMA(ar[g & 1][s2 * 2],     bv1, a01);                               \
          MFMA(ar[g & 1][s2 * 2 + 1], bv1, a11);                               \
        }                                                                      \
      }                                                                        \
    }                                                                          \
  }

// ---------------- fused gather + conv2d #1 (MFMA) -> y1t[b][w][d][hi] ------
// single-buffer LDS (33.8 KB) -> 4 blocks/CU; stage->sync->compute->sync per kw
__global__ __launch_bounds__(256, 4) void conv2d1_mfma(
    const ushort* __restrict__ embt, const int* __restrict__ wb,
    const int* __restrict__ wlen, const ushort* __restrict__ Wc,
    const float* __restrict__ cb, ushort* __restrict__ y1t,
    const ushort* __restrict__ zp) {
  extern __shared__ __align__(16) ushort smem[];   // 16896 ushorts
  const int bid = blockIdx.x;
  const int nid = (bid & 7) * 256 + (bid >> 3);    // XCD-chunked (2048 % 8 == 0)
  const int b = nid >> 6, w = nid & 63;
  const int tid = threadIdx.x;
  const int lane = tid & 63, wv = tid >> 6;
  const int l31 = lane & 31, half = lane >> 5;
  const int m_w = (wv >> 1) * 64, n_w = (wv & 1) * 64;

  int stv[5], duv[5];
  const int wl = wlen[b];
  #pragma unroll
  for (int i = 0; i < 5; ++i) {
    int wq = w + i - 2;
    bool ok = ((unsigned)wq < WW) && (wq < wl);
    int st = ok ? wb[b * 128 + wq] : 0;
    int en = ok ? wb[b * 128 + 64 + wq] : 0;
    stv[i] = st;
    duv[i] = ok ? min(en - st, 128) : 0;
  }
  // y1[w,d] is exactly relu(cb1) (const per channel) for d >= max5(dur)+2
  int dcap = 0;
  #pragma unroll
  for (int i = 0; i < 5; ++i) dcap = max(dcap, duv[i]);
  const int NT1 = min(4, max(1, (dcap + 2 + 31) >> 5));
  const int rstage = min(132, NT1 * 32 + 4);
  const int t0a = n_w >> 5;
  const bool act0 = t0a < NT1, act1 = t0a + 1 < NT1;

#define STAGE1(KW)                                                             \
  {                                                                            \
    const int st_ = stv[KW], du_ = duv[KW];                                    \
    _Pragma("unroll")                                                          \
    for (int it = 0; it < 9; ++it) {                                           \
      int slot = it * 256 + tid;                                               \
      if (slot < 2112) {                                                       \
        int row = slot >> 4;                                                   \
        if (row < rstage) {                                                    \
          int bsw = (slot & 15) ^ (row & 15);                                  \
          int dq = row - 2;                                                    \
          const ushort* src = ((unsigned)dq < (unsigned)du_)                   \
              ? embt + (((size_t)(b * TT + st_ + dq)) << 7) + bsw * 8 : zp;    \
          g2l16(src, smem + slot * 8);                                         \
        }                                                                      \
      }                                                                        \
    }                                                                          \
  }

  f32x16 a00 = 0.f, a01 = 0.f, a10 = 0.f, a11 = 0.f;
  const bf16x8* Ap = (const bf16x8*)Wc;

  STAGE1(0);
  __syncthreads();
  #pragma unroll
  for (int kw = 0; kw < 5; ++kw) {
    if (act1)      { COMPUTE2D(kw, smem, 2); }
    else if (act0) { COMPUTE2D(kw, smem, 1); }
    __syncthreads();
    if (kw < 4) {
      switch (kw + 1) {     // compile-time under unroll
        case 1: STAGE1(1); break;
        case 2: STAGE1(2); break;
        case 3: STAGE1(3); break;
        case 4: STAGE1(4); break;
      }
      __syncthreads();
    }
  }
#undef STAGE1

  if (act0) {
    dump_tile(a00, n_w + l31, m_w,      half, cb, true, smem);
    dump_tile(a10, n_w + l31, m_w + 32, half, cb, true, smem);
  }
  if (act1) {
    dump_tile(a01, n_w + 32 + l31, m_w,      half, cb, true, smem);
    dump_tile(a11, n_w + 32 + l31, m_w + 32, half, cb, true, smem);
  }
  __syncthreads();
  // const vector for d >= NT1*32 (this thread's fixed 8 channels)
  bf16x8 cv;
  {
    int blkc = tid & 15;
    #pragma unroll
    for (int j = 0; j < 8; ++j)
      ((ushort*)&cv)[j] = bf16b(fmaxf(cb[blkc * 8 + j], 0.f));
  }
  #pragma unroll
  for (int it = 0; it < 8; ++it) {
    int i = it * 256 + tid;
    int d = i >> 4, blk = i & 15;
    bf16x8 v = (d < NT1 * 32)
        ? *(const bf16x8*)&smem[d * 128 + ((blk ^ (d & 15)) << 3)] : cv;
    *(bf16x8*)(y1t + (((size_t)(b * WW + w) * DD + d) << 7) + blk * 8) = v;
  }
}

// ---------------- conv2d #2 (MFMA) + relu + einsum(lw) + relu -> z f32 -----
__global__ __launch_bounds__(256, 4) void conv2d2_mfma(
    const ushort* __restrict__ y1t, const int* __restrict__ wb,
    const int* __restrict__ wlen, const ushort* __restrict__ Wc,
    const float* __restrict__ cb, const float* __restrict__ lw,
    const float* __restrict__ lb, const float* __restrict__ T2,
    const float* __restrict__ Ls, float* __restrict__ z,
    const ushort* __restrict__ zp) {
  extern __shared__ __align__(16) ushort smem[];   // 16896 ushorts
  const int bid = blockIdx.x;
  const int nid = (bid & 7) * 256 + (bid >> 3);
  const int b = nid >> 6, w = nid & 63;
  const int tid = threadIdx.x;
  const int lane = tid & 63, wv = tid >> 6;
  const int l31 = lane & 31, half = lane >> 5;
  const int m_w = (wv >> 1) * 64, n_w = (wv & 1) * 64;

  // y2[w,d] is analytically const for d >= max over w±4 (9 words) of dur + 4
  int dmax = 0;
  const int wl = wlen[b];
  #pragma unroll
  for (int i = 0; i < 9; ++i) {
    int wq = w + i - 4;
    if ((unsigned)wq < WW && wq < wl) {
      int du = min(wb[b * 128 + 64 + wq] - wb[b * 128 + wq], 128);
      dmax = max(dmax, du);
    }
  }
  const int NT2 = min(4, max(1, (dmax + 4 + 31) >> 5));
  const int rstage = min(132, NT2 * 32 + 4);
  const int t0a = n_w >> 5;
  const bool act0 = t0a < NT2, act1 = t0a + 1 < NT2;

#define STAGE2(KW)                                                             \
  {                                                                            \
    const int wq_ = w + (KW) - 2;                                              \
    const bool wok_ = (unsigned)wq_ < WW;                                      \
    _Pragma("unroll")                                                          \
    for (int it = 0; it < 9; ++it) {                                           \
      int slot = it * 256 + tid;                                               \
      if (slot < 2112) {                                                       \
        int row = slot >> 4;                                                   \
        if (row < rstage) {                                                    \
          int bsw = (slot & 15) ^ (row & 15);                                  \
          int dq = row - 2;                                                    \
          const ushort* src = (wok_ && (unsigned)dq < (unsigned)DD)            \
              ? y1t + (((size_t)(b * WW + wq_) * DD + dq) << 7) + bsw * 8 : zp;\
          g2l16(src, smem + slot * 8);                                         \
        }                                                                      \
      }                                                                        \
    }                                                                          \
  }

  f32x16 a00 = 0.f, a01 = 0.f, a10 = 0.f, a11 = 0.f;
  const bf16x8* Ap = (const bf16x8*)Wc;

  STAGE2(0);
  __syncthreads();
  #pragma unroll
  for (int kw = 0; kw < 5; ++kw) {
    if (act1)      { COMPUTE2D(kw, smem, 2); }
    else if (act0) { COMPUTE2D(kw, smem, 1); }
    __syncthreads();
    if (kw < 4) {
      switch (kw + 1) {
        case 1: STAGE2(1); break;
        case 2: STAGE2(2); break;
        case 3: STAGE2(3); break;
        case 4: STAGE2(4); break;
      }
      __syncthreads();
    }
  }
#undef STAGE2

  // epilogue: relu(acc+cb)*lw over computed d, reduce; const tail analytic
  float* s_red = (float*)smem;            // [128][2]
  const float lw0 = lw[n_w + l31], lw1 = lw[n_w + 32 + l31];
  #pragma unroll
  for (int r = 0; r < 16; ++r) {
    int rowoff = (r & 3) + 8 * (r >> 2) + 4 * half;
    {
      int ho = m_w + rowoff;
      float c = cb[ho];
      float v = (act0 ? fmaxf(a00[r] + c, 0.f) * lw0 : 0.f)
              + (act1 ? fmaxf(a01[r] + c, 0.f) * lw1 : 0.f);
      v += __shfl_xor(v, 1); v += __shfl_xor(v, 2); v += __shfl_xor(v, 4);
      v += __shfl_xor(v, 8); v += __shfl_xor(v, 16);
      if (l31 == 0) s_red[ho * 2 + (wv & 1)] = v;
    }
    {
      int ho = m_w + 32 + rowoff;
      float c = cb[ho];
      float v = (act0 ? fmaxf(a10[r] + c, 0.f) * lw0 : 0.f)
              + (act1 ? fmaxf(a11[r] + c, 0.f) * lw1 : 0.f);
      v += __shfl_xor(v, 1); v += __shfl_xor(v, 2); v += __shfl_xor(v, 4);
      v += __shfl_xor(v, 8); v += __shfl_xor(v, 16);
      if (l31 == 0) s_red[ho * 2 + (wv & 1)] = v;
    }
  }
  __syncthreads();
  if (tid < HH) {
    int ho = tid;
    float hiv = 0.f;
    if (NT2 < 4) {
      float ccA = 0.f, ccB = 0.f, ccC = 0.f;
      #pragma unroll
      for (int kw = 0; kw < 5; ++kw) {
        int wq = w + kw - 2;
        if ((unsigned)wq < WW) {
          ccA += T2[(ho * 5 + kw) * 3 + 0];
          ccB += T2[(ho * 5 + kw) * 3 + 1];
          ccC += T2[(ho * 5 + kw) * 3 + 2];
        }
      }
      float c = cb[ho];
      float l126 = lw[126], l127 = lw[127];
      hiv = fmaxf(ccA + c, 0.f) * (Ls[NT2] - l126 - l127)
          + fmaxf(ccB + c, 0.f) * l126
          + fmaxf(ccC + c, 0.f) * l127;
    }
    float zz = fmaxf(s_red[ho * 2] + s_red[ho * 2 + 1] + hiv + lb[0], 0.f);
    z[(b * HH + ho) * WW + w] = zz;
  }
}

// ---------------- final conv2d (1 out channel, D-dim=1 -> only kd=2) -------
__global__ __launch_bounds__(64) void final_k(const float* __restrict__ z,
        const float* __restrict__ cw3, const float* __restrict__ cb3,
        float* __restrict__ out) {
  const int b = blockIdx.x;
  const int w = threadIdx.x;
  float acc = cb3[0];
  for (int hi = 0; hi < HH; ++hi) {
    const float* zp = z + (b * HH + hi) * WW;
    #pragma unroll
    for (int kw = 0; kw < 5; ++kw) {
      int ww = w + kw - 2;
      if (ww >= 0 && ww < WW) acc += cw3[hi * 25 + kw * 5 + 2] * zp[ww];
    }
  }
  out[b * WW + w] = acc;
}

extern "C" void kernel_launch(void* const* d_in, const int* in_sizes, int n_in,
                              void* d_out, int out_size, void* d_ws, size_t ws_size,
                              hipStream_t stream) {
  const float* features = (const float*)d_in[0];
  const int*   wbnd     = (const int*)d_in[1];
  const int*   wlen     = (const int*)d_in[2];
  const float* w1  = (const float*)d_in[3];
  const float* b1  = (const float*)d_in[4];
  const float* w2  = (const float*)d_in[5];
  const float* b2  = (const float*)d_in[6];
  const float* w3  = (const float*)d_in[7];
  const float* b3  = (const float*)d_in[8];
  const float* cw1 = (const float*)d_in[9];
  const float* cb1 = (const float*)d_in[10];
  const float* cw2 = (const float*)d_in[11];
  const float* cb2 = (const float*)d_in[12];
  const float* lw  = (const float*)d_in[13];
  const float* lb  = (const float*)d_in[14];
  const float* cw3 = (const float*)d_in[15];
  const float* cb3 = (const float*)d_in[16];
  float* out = (float*)d_out;

  char* ws = (char*)d_ws;
  ushort* ft   = (ushort*)(ws + 0);           // 16,777,216 B  [b][t][128]
  ushort* x1t  = (ushort*)(ws + 16777216);
  ushort* x2t  = (ushort*)(ws + 33554432);
  ushort* embt = (ushort*)(ws + 0);           // over ft (dead after layer1)
  ushort* y1t  = (ushort*)(ws + 16777216);    // 67,108,864 B (x1t/x2t dead)
  float*  z    = (float*)(ws + 83886080);     // 1,048,576 B
  ushort* Wb1  = (ushort*)(ws + 84934656);    // 102,400 B
  ushort* Wb2  = (ushort*)(ws + 85037056);    // 163,840 B
  ushort* Wb3  = (ushort*)(ws + 85200896);    // 163,840 B
  ushort* Wc1  = (ushort*)(ws + 85364736);    // 819,200 B
  ushort* Wc2  = (ushort*)(ws + 86183936);    // 819,200 B
  ushort* zp   = (ushort*)(ws + 87003136);    // 4,096 B zero page
  float*  T2   = (float*)(ws + 87007232);     // 7,680 B (640*3 f32)
  float*  Ls   = (float*)(ws + 87014912);     // 20 B

  const int DYN = 16896 * 2;                  // 33,792 B dynamic LDS (1 slab)
  hipFuncSetAttribute((const void*)conv2d1_mfma,
                      hipFuncAttributeMaxDynamicSharedMemorySize, DYN);
  hipFuncSetAttribute((const void*)conv2d2_mfma,
                      hipFuncAttributeMaxDynamicSharedMemorySize, DYN);

  prep_all<<<5068, 256, 0, stream>>>(features, w1, w2, w3, cw1, cw2, cb1, lw,
                                     ft, Wb1, Wb2, Wb3, Wc1, Wc2, T2, Ls, zp);
  conv1d_mfma<5, 1><<<1024, 256, 0, stream>>>(ft, Wb1, b1, x1t, zp);
  conv1d_mfma<8, 1><<<1024, 256, 0, stream>>>(x1t, Wb2, b2, x2t, zp);
  conv1d_mfma<8, 0><<<1024, 256, 0, stream>>>(x2t, Wb3, b3, embt, zp);
  conv2d1_mfma<<<BB * WW, 256, DYN, stream>>>(embt, wbnd, wlen, Wc1, cb1, y1t, zp);
  conv2d2_mfma<<<BB * WW, 256, DYN, stream>>>(y1t, wbnd, wlen, Wc2, cb2, lw, lb,
                                              T2, Ls, z, zp);
  final_k<<<BB, 64, 0, stream>>>(z, cw3, cb3, out);
}

// Round 10
// 341.601 us; speedup vs baseline: 1.5144x; 1.2736x over previous
//
#include <hip/hip_runtime.h>
#include <hip/hip_bf16.h>

#define BB 32
#define TT 2048
#define MELS 80
#define HH 128
#define WW 64
#define DD 128

using bf16x8 = __attribute__((ext_vector_type(8))) short;
using f32x16 = __attribute__((ext_vector_type(16))) float;
using u16x4  = __attribute__((ext_vector_type(4))) ushort;

#define MFMA(av, bv, acc) acc = __builtin_amdgcn_mfma_f32_32x32x16_bf16(av, bv, acc, 0, 0, 0)

__device__ __forceinline__ ushort bf16b(float f) {
  __hip_bfloat16 h = __float2bfloat16(f);
  return *(ushort*)&h;
}

// async global->LDS 16B DMA (linear LDS dest; swizzle goes on the SOURCE)
__device__ __forceinline__ void g2l16(const ushort* g, ushort* l) {
  __builtin_amdgcn_global_load_lds((const __attribute__((address_space(1))) void*)g,
                                   (__attribute__((address_space(3))) void*)l, 16, 0, 0);
}

// Epilogue helper: scatter one 32x32 C-tile into LDS s_y[col][row] (bf16,
// 4-bit XOR swizzle on 16B blocks) with bias+optional relu.
__device__ __forceinline__ void dump_tile(const f32x16& a, int tl, int mb, int half,
                                          const float* __restrict__ bias, bool relu,
                                          ushort* s_y) {
  #pragma unroll
  for (int q = 0; q < 4; ++q) {
    int ho0 = mb + 8 * q + 4 * half;
    u16x4 p;
    #pragma unroll
    for (int j = 0; j < 4; ++j) {
      float v = a[q * 4 + j] + bias[ho0 + j];
      if (relu) v = fmaxf(v, 0.f);
      p[j] = bf16b(v);
    }
    *(u16x4*)&s_y[tl * 128 + (((ho0 >> 3) ^ (tl & 15)) << 3) + (ho0 & 7)] = p;
  }
}

// ---------------- fused prep: tr_feat + 3x repack1d + 2x repack2d + T2/Ls + zp
__global__ __launch_bounds__(256) void prep_all(
    const float* __restrict__ features,
    const float* __restrict__ w1, const float* __restrict__ w2,
    const float* __restrict__ w3, const float* __restrict__ cw1,
    const float* __restrict__ cw2, const float* __restrict__ cb1,
    const float* __restrict__ lw,
    ushort* __restrict__ ft, ushort* __restrict__ Wb1, ushort* __restrict__ Wb2,
    ushort* __restrict__ Wb3, ushort* __restrict__ Wc1, ushort* __restrict__ Wc2,
    float* __restrict__ T2, float* __restrict__ Ls, ushort* __restrict__ zp) {
  __shared__ float s[MELS][65];
  const int bb = blockIdx.x, tid = threadIdx.x;
  if (bb < 1024) {
    // features [b][80][t] f32 -> ft [b][t][128] bf16 (c>=80 -> 0)
    const int b = bb >> 5, t0 = (bb & 31) * 64;
    for (int i = tid; i < MELS * 64; i += 256) {
      int c = i >> 6, t = i & 63;
      s[c][t] = features[(b * MELS + c) * TT + t0 + t];
    }
    __syncthreads();
    for (int i = tid; i < 64 * 128; i += 256) {
      int t = i >> 7, c = i & 127;
      float v = (c < MELS) ? s[c][t] : 0.f;
      ft[(b * TT + t0 + t) * 128 + c] = bf16b(v);
    }
  } else if (bb < 1864) {
    // repack1d: w[m][c][kw] -> Wb[kw][ss][half][m][e], c = ss*16+half*8+e
    int rel, NSS, C; const float* w; ushort* Wb;
    if (bb < 1224)      { rel = bb - 1024; NSS = 5; C = MELS; w = w1; Wb = Wb1; }
    else if (bb < 1544) { rel = bb - 1224; NSS = 8; C = HH;   w = w2; Wb = Wb2; }
    else                { rel = bb - 1544; NSS = 8; C = HH;   w = w3; Wb = Wb3; }
    int i = rel * 256 + tid;
    int e = i & 7, m = (i >> 3) & 127, half = (i >> 10) & 1;
    int r = i >> 11;
    int ss = r % NSS, kw = r / NSS;
    int c = ss * 16 + half * 8 + e;
    Wb[i] = bf16b(w[(m * C + c) * 5 + kw]);
  } else if (bb < 5064) {
    // repack2d: cw[m][hi][kw][kd] -> Wc[kd][kw][ss][half][m][e]
    int rel; const float* cw; ushort* Wc;
    if (bb < 3464) { rel = bb - 1864; cw = cw1; Wc = Wc1; }
    else           { rel = bb - 3464; cw = cw2; Wc = Wc2; }
    int i = rel * 256 + tid;
    int e = i & 7, m = (i >> 3) & 127, half = (i >> 10) & 1, ss = (i >> 11) & 7;
    int r = i >> 14;
    int kw = r % 5, kd = r / 5;
    int hi = ss * 16 + half * 8 + e;
    Wc[i] = bf16b(cw[((m * HH + hi) * 5 + kw) * 5 + kd]);
  } else if (bb < 5067) {
    // T2[(ho*5+kw)*3+v]: v=0 kd0..4; v=1 kd0..3; v=2 kd0..2.  Ls[c]=sum_{d>=32c} lw
    int i = (bb - 5064) * 256 + tid;
    if (i < 640) {
      int ho = i / 5, kw = i - ho * 5;
      float sA = 0.f, sB = 0.f, sC = 0.f;
      for (int hi = 0; hi < HH; ++hi) {
        float yc = fmaxf(cb1[hi], 0.f);
        const float* p = cw2 + ((ho * HH + hi) * 5 + kw) * 5;
        float c012 = p[0] + p[1] + p[2];
        sC += c012 * yc;
        sB += (c012 + p[3]) * yc;
        sA += (c012 + p[3] + p[4]) * yc;
      }
      T2[i * 3 + 0] = sA; T2[i * 3 + 1] = sB; T2[i * 3 + 2] = sC;
    } else if (i < 645) {
      int c = i - 640;
      float sv = 0.f;
      for (int d = c * 32; d < 128; ++d) sv += lw[d];
      Ls[c] = sv;   // Ls[4] = 0
    }
  } else {
    *(bf16x8*)(zp + tid * 8) = (short)0;   // 4096 B zero page
  }
}

// ---------------- conv1d via MFMA: xt[b][t][128] -> yt[b][t][128] ----------
// t-tile 64, grid 1024, slab 68 rows (17.4 KB) -> 4 blocks/CU, 16 waves/CU.
template<int NSS, int RELU>
__global__ __launch_bounds__(256) void conv1d_mfma(
    const ushort* __restrict__ xt, const ushort* __restrict__ Wb,
    const float* __restrict__ bias, ushort* __restrict__ yt,
    const ushort* __restrict__ zp) {
  __shared__ __align__(16) ushort s_x[1088 * 8];
  const int bid = blockIdx.x;
  const int nid = (bid & 7) * 128 + (bid >> 3);   // XCD-chunked (1024 % 8 == 0)
  const int b = nid >> 5;
  const int t0 = (nid & 31) << 6;
  const int tid = threadIdx.x;
  const int lane = tid & 63, wv = tid >> 6;
  const int l31 = lane & 31, half = lane >> 5;
  const int m_w = (wv >> 1) * 64, n32 = (wv & 1) * 32;

  #pragma unroll
  for (int it = 0; it < 5; ++it) {
    int slot = it * 256 + tid;
    if (slot < 1088) {
      int row = slot >> 4, bsw = (slot & 15) ^ (row & 15);
      int t = t0 + row - 2;
      const ushort* src = ((unsigned)t < TT)
          ? xt + (((size_t)(b * TT + t)) << 7) + bsw * 8 : zp;
      g2l16(src, s_x + slot * 8);
    }
  }
  __syncthreads();

  f32x16 a0 = 0.f, a1 = 0.f;
  const bf16x8* Ap = (const bf16x8*)Wb;
  constexpr int G = 5 * NSS;
  #pragma unroll
  for (int g = 0; g < G; ++g) {
    const int kw = g / NSS, ss = g % NSS;
    int r0 = n32 + l31 + kw;
    int blk = ss * 2 + half;
    bf16x8 bv = *(const bf16x8*)&s_x[r0 * 128 + ((blk ^ (r0 & 15)) << 3)];
    int ai = ((kw * NSS + ss) * 2 + half) * 128 + m_w + l31;
    MFMA(Ap[ai],      bv, a0);
    MFMA(Ap[ai + 32], bv, a1);
  }
  __syncthreads();
  dump_tile(a0, n32 + l31, m_w,      half, bias, RELU != 0, s_x);
  dump_tile(a1, n32 + l31, m_w + 32, half, bias, RELU != 0, s_x);
  __syncthreads();
  #pragma unroll
  for (int it = 0; it < 4; ++it) {
    int i = it * 256 + tid;        // 64 t x 16 blk = 1024 slots
    int tl = i >> 4, blk = i & 15;
    bf16x8 v = *(const bf16x8*)&s_x[tl * 128 + ((blk ^ (tl & 15)) << 3)];
    *(bf16x8*)(yt + (((size_t)(b * TT + t0 + tl)) << 7) + blk * 8) = v;
  }
}

// ---- per-wave compute of one kw slab: M64 x N64, A-regs double-buffered ----
// NB = active 64-wide n-blocks for this wave (2 = both, 1 = bv0 only).
// setprio(1) around the MFMA cluster (T5): blocks on a CU sit at different
// phases (stage vs compute) so the scheduler has real arbitration to do.
#define COMPUTE2D(KW, BUF, NB)                                                 \
  {                                                                            \
    bf16x8 ar[2][8];                                                           \
    _Pragma("unroll")                                                          \
    for (int j = 0; j < 8; ++j)                                                \
      ar[0][j] = Ap[(((0 * 5 + (KW)) * 8 + (j >> 1)) * 2 + half) * 128 +       \
                    m_w + l31 + (j & 1) * 32];                                 \
    __builtin_amdgcn_s_setprio(1);                                             \
    _Pragma("unroll")                                                          \
    for (int g = 0; g < 10; ++g) {                                             \
      int kd = g >> 1, sh = (g & 1) * 4;                                       \
      if (g < 9) {                                                             \
        int kd2 = (g + 1) >> 1, sh2 = ((g + 1) & 1) * 4;                       \
        _Pragma("unroll")                                                      \
        for (int j = 0; j < 8; ++j)                                            \
          ar[(g + 1) & 1][j] = Ap[(((kd2 * 5 + (KW)) * 8 + sh2 + (j >> 1)) * 2 \
                                   + half) * 128 + m_w + l31 + (j & 1) * 32];  \
      }                                                                        \
      _Pragma("unroll")                                                        \
      for (int s2 = 0; s2 < 4; ++s2) {                                         \
        int ss = sh + s2;                                                      \
        int r0 = n_w + l31 + kd;                                               \
        int blk = ss * 2 + half;                                               \
        bf16x8 bv0 = *(const bf16x8*)&(BUF)[r0 * 128 + ((blk ^ (r0 & 15)) << 3)]; \
        MFMA(ar[g & 1][s2 * 2],     bv0, a00);                                 \
        MFMA(ar[g & 1][s2 * 2 + 1], bv0, a10);                                 \
        if ((NB) > 1) {                                                        \
          int r1 = r0 + 32;                                                    \
          bf16x8 bv1 = *(const bf16x8*)&(BUF)[r1 * 128 + ((blk ^ (r1 & 15)) << 3)]; \
          MFMA(ar[g & 1][s2 * 2],     bv1, a01);                               \
          MFMA(ar[g & 1][s2 * 2 + 1], bv1, a11);                               \
        }                                                                      \
      }                                                                        \
    }                                                                          \
    __builtin_amdgcn_s_setprio(0);                                             \
  }

// ---------------- fused gather + conv2d #1 (MFMA) -> y1t[b][w][d][hi] ------
// single-buffer LDS (33.8 KB) -> 4 blocks/CU. Per-kw EXACT zero-skipping:
// word kw's slab is zero beyond dur_kw, so tile T gets a contribution from kw
// only if T*32 < dur_kw+2; gate compute AND staging rows per kw.
__global__ __launch_bounds__(256, 4) void conv2d1_mfma(
    const ushort* __restrict__ embt, const int* __restrict__ wb,
    const int* __restrict__ wlen, const ushort* __restrict__ Wc,
    const float* __restrict__ cb, ushort* __restrict__ y1t,
    const ushort* __restrict__ zp) {
  extern __shared__ __align__(16) ushort smem[];   // 16896 ushorts
  const int bid = blockIdx.x;
  const int nid = (bid & 7) * 256 + (bid >> 3);    // XCD-chunked (2048 % 8 == 0)
  const int b = nid >> 6, w = nid & 63;
  const int tid = threadIdx.x;
  const int lane = tid & 63, wv = tid >> 6;
  const int l31 = lane & 31, half = lane >> 5;
  const int m_w = (wv >> 1) * 64, n_w = (wv & 1) * 64;

  int stv[5], duv[5];
  const int wl = wlen[b];
  #pragma unroll
  for (int i = 0; i < 5; ++i) {
    int wq = w + i - 2;
    bool ok = ((unsigned)wq < WW) && (wq < wl);
    int st = ok ? wb[b * 128 + wq] : 0;
    int en = ok ? wb[b * 128 + 64 + wq] : 0;
    stv[i] = st;
    duv[i] = ok ? min(en - st, 128) : 0;
  }
  // y1[w,d] is exactly relu(cb1) (const per channel) for d >= max5(dur)+2
  int dcap = 0;
  #pragma unroll
  for (int i = 0; i < 5; ++i) dcap = max(dcap, duv[i]);
  const int NT1 = min(4, max(1, (dcap + 2 + 31) >> 5));
  const int rstage = min(132, NT1 * 32 + 4);
  const int t0a = n_w >> 5;
  const bool act0 = t0a < NT1, act1 = t0a + 1 < NT1;

#define STAGE1(KW)                                                             \
  {                                                                            \
    const int st_ = stv[KW], du_ = duv[KW];                                    \
    if (du_ > 0) {                                                             \
      const int rs_ = min(rstage, (((du_ + 33) >> 5) << 5) + 4);               \
      _Pragma("unroll")                                                        \
      for (int it = 0; it < 9; ++it) {                                         \
        int slot = it * 256 + tid;                                             \
        if (slot < 2112) {                                                     \
          int row = slot >> 4;                                                 \
          if (row < rs_) {                                                     \
            int bsw = (slot & 15) ^ (row & 15);                                \
            int dq = row - 2;                                                  \
            const ushort* src = ((unsigned)dq < (unsigned)du_)                 \
                ? embt + (((size_t)(b * TT + st_ + dq)) << 7) + bsw * 8 : zp;  \
            g2l16(src, smem + slot * 8);                                       \
          }                                                                    \
        }                                                                      \
      }                                                                        \
    }                                                                          \
  }

  f32x16 a00 = 0.f, a01 = 0.f, a10 = 0.f, a11 = 0.f;
  const bf16x8* Ap = (const bf16x8*)Wc;

  STAGE1(0);
  __syncthreads();
  #pragma unroll
  for (int kw = 0; kw < 5; ++kw) {
    const int du = duv[kw];
    const bool a1k = act1 && (du + 2 > n_w + 32);
    const bool a0k = act0 && (du > 0) && (du + 2 > n_w);
    if (a1k)      { COMPUTE2D(kw, smem, 2); }
    else if (a0k) { COMPUTE2D(kw, smem, 1); }
    __syncthreads();
    if (kw < 4) {
      switch (kw + 1) {     // compile-time under unroll
        case 1: STAGE1(1); break;
        case 2: STAGE1(2); break;
        case 3: STAGE1(3); break;
        case 4: STAGE1(4); break;
      }
      __syncthreads();
    }
  }
#undef STAGE1

  if (act0) {
    dump_tile(a00, n_w + l31, m_w,      half, cb, true, smem);
    dump_tile(a10, n_w + l31, m_w + 32, half, cb, true, smem);
  }
  if (act1) {
    dump_tile(a01, n_w + 32 + l31, m_w,      half, cb, true, smem);
    dump_tile(a11, n_w + 32 + l31, m_w + 32, half, cb, true, smem);
  }
  __syncthreads();
  // const vector for d >= NT1*32 (this thread's fixed 8 channels)
  bf16x8 cv;
  {
    int blkc = tid & 15;
    #pragma unroll
    for (int j = 0; j < 8; ++j)
      ((ushort*)&cv)[j] = bf16b(fmaxf(cb[blkc * 8 + j], 0.f));
  }
  #pragma unroll
  for (int it = 0; it < 8; ++it) {
    int i = it * 256 + tid;
    int d = i >> 4, blk = i & 15;
    bf16x8 v = (d < NT1 * 32)
        ? *(const bf16x8*)&smem[d * 128 + ((blk ^ (d & 15)) << 3)] : cv;
    *(bf16x8*)(y1t + (((size_t)(b * WW + w) * DD + d) << 7) + blk * 8) = v;
  }
}

// ---------------- conv2d #2 (MFMA) + relu + einsum(lw) + relu -> z f32 -----
__global__ __launch_bounds__(256, 4) void conv2d2_mfma(
    const ushort* __restrict__ y1t, const int* __restrict__ wb,
    const int* __restrict__ wlen, const ushort* __restrict__ Wc,
    const float* __restrict__ cb, const float* __restrict__ lw,
    const float* __restrict__ lb, const float* __restrict__ T2,
    const float* __restrict__ Ls, float* __restrict__ z,
    const ushort* __restrict__ zp) {
  extern __shared__ __align__(16) ushort smem[];   // 16896 ushorts
  const int bid = blockIdx.x;
  const int nid = (bid & 7) * 256 + (bid >> 3);
  const int b = nid >> 6, w = nid & 63;
  const int tid = threadIdx.x;
  const int lane = tid & 63, wv = tid >> 6;
  const int l31 = lane & 31, half = lane >> 5;
  const int m_w = (wv >> 1) * 64, n_w = (wv & 1) * 64;

  // y2[w,d] is analytically const for d >= max over w±4 (9 words) of dur + 4
  int dmax = 0;
  const int wl = wlen[b];
  #pragma unroll
  for (int i = 0; i < 9; ++i) {
    int wq = w + i - 4;
    if ((unsigned)wq < WW && wq < wl) {
      int du = min(wb[b * 128 + 64 + wq] - wb[b * 128 + wq], 128);
      dmax = max(dmax, du);
    }
  }
  const int NT2 = min(4, max(1, (dmax + 4 + 31) >> 5));
  const int rstage = min(132, NT2 * 32 + 4);
  const int t0a = n_w >> 5;
  const bool act0 = t0a < NT2, act1 = t0a + 1 < NT2;

#define STAGE2(KW)                                                             \
  {                                                                            \
    const int wq_ = w + (KW) - 2;                                              \
    if ((unsigned)wq_ < WW) {                                                  \
      _Pragma("unroll")                                                        \
      for (int it = 0; it < 9; ++it) {                                         \
        int slot = it * 256 + tid;                                             \
        if (slot < 2112) {                                                     \
          int row = slot >> 4;                                                 \
          if (row < rstage) {                                                  \
            int bsw = (slot & 15) ^ (row & 15);                                \
            int dq = row - 2;                                                  \
            const ushort* src = ((unsigned)dq < (unsigned)DD)                  \
                ? y1t + (((size_t)(b * WW + wq_) * DD + dq) << 7) + bsw * 8 : zp;\
            g2l16(src, smem + slot * 8);                                       \
          }                                                                    \
        }                                                                      \
      }                                                                        \
    }                                                                          \
  }

  f32x16 a00 = 0.f, a01 = 0.f, a10 = 0.f, a11 = 0.f;
  const bf16x8* Ap = (const bf16x8*)Wc;

  STAGE2(0);
  __syncthreads();
  #pragma unroll
  for (int kw = 0; kw < 5; ++kw) {
    const bool kok = (unsigned)(w + kw - 2) < WW;   // OOB slab is all-zero: skip
    if (kok && act1)      { COMPUTE2D(kw, smem, 2); }
    else if (kok && act0) { COMPUTE2D(kw, smem, 1); }
    __syncthreads();
    if (kw < 4) {
      switch (kw + 1) {
        case 1: STAGE2(1); break;
        case 2: STAGE2(2); break;
        case 3: STAGE2(3); break;
        case 4: STAGE2(4); break;
      }
      __syncthreads();
    }
  }
#undef STAGE2

  // epilogue: relu(acc+cb)*lw over computed d, reduce; const tail analytic
  float* s_red = (float*)smem;            // [128][2]
  const float lw0 = lw[n_w + l31], lw1 = lw[n_w + 32 + l31];
  #pragma unroll
  for (int r = 0; r < 16; ++r) {
    int rowoff = (r & 3) + 8 * (r >> 2) + 4 * half;
    {
      int ho = m_w + rowoff;
      float c = cb[ho];
      float v = (act0 ? fmaxf(a00[r] + c, 0.f) * lw0 : 0.f)
              + (act1 ? fmaxf(a01[r] + c, 0.f) * lw1 : 0.f);
      v += __shfl_xor(v, 1); v += __shfl_xor(v, 2); v += __shfl_xor(v, 4);
      v += __shfl_xor(v, 8); v += __shfl_xor(v, 16);
      if (l31 == 0) s_red[ho * 2 + (wv & 1)] = v;
    }
    {
      int ho = m_w + 32 + rowoff;
      float c = cb[ho];
      float v = (act0 ? fmaxf(a10[r] + c, 0.f) * lw0 : 0.f)
              + (act1 ? fmaxf(a11[r] + c, 0.f) * lw1 : 0.f);
      v += __shfl_xor(v, 1); v += __shfl_xor(v, 2); v += __shfl_xor(v, 4);
      v += __shfl_xor(v, 8); v += __shfl_xor(v, 16);
      if (l31 == 0) s_red[ho * 2 + (wv & 1)] = v;
    }
  }
  __syncthreads();
  if (tid < HH) {
    int ho = tid;
    float hiv = 0.f;
    if (NT2 < 4) {
      float ccA = 0.f, ccB = 0.f, ccC = 0.f;
      #pragma unroll
      for (int kw = 0; kw < 5; ++kw) {
        int wq = w + kw - 2;
        if ((unsigned)wq < WW) {
          ccA += T2[(ho * 5 + kw) * 3 + 0];
          ccB += T2[(ho * 5 + kw) * 3 + 1];
          ccC += T2[(ho * 5 + kw) * 3 + 2];
        }
      }
      float c = cb[ho];
      float l126 = lw[126], l127 = lw[127];
      hiv = fmaxf(ccA + c, 0.f) * (Ls[NT2] - l126 - l127)
          + fmaxf(ccB + c, 0.f) * l126
          + fmaxf(ccC + c, 0.f) * l127;
    }
    float zz = fmaxf(s_red[ho * 2] + s_red[ho * 2 + 1] + hiv + lb[0], 0.f);
    z[(b * HH + ho) * WW + w] = zz;
  }
}

// ---------------- final conv2d (1 out channel, D-dim=1 -> only kd=2) -------
// block per b; 256 threads = 4 hi-groups x 64 w; LDS reduce over groups
__global__ __launch_bounds__(256) void final_k(const float* __restrict__ z,
        const float* __restrict__ cw3, const float* __restrict__ cb3,
        float* __restrict__ out) {
  __shared__ float sred[4][64];
  const int b = blockIdx.x;
  const int tid = threadIdx.x;
  const int w = tid & 63, g = tid >> 6;
  float acc = 0.f;
  for (int hi = g * 32; hi < g * 32 + 32; ++hi) {
    const float* zp_ = z + (b * HH + hi) * WW;
    const float* cp = cw3 + hi * 25 + 2;
    #pragma unroll
    for (int kw = 0; kw < 5; ++kw) {
      int ww = w + kw - 2;
      if ((unsigned)ww < WW) acc += cp[kw * 5] * zp_[ww];
    }
  }
  sred[g][w] = acc;
  __syncthreads();
  if (tid < 64)
    out[b * WW + w] = cb3[0] + sred[0][w] + sred[1][w] + sred[2][w] + sred[3][w];
}

extern "C" void kernel_launch(void* const* d_in, const int* in_sizes, int n_in,
                              void* d_out, int out_size, void* d_ws, size_t ws_size,
                              hipStream_t stream) {
  const float* features = (const float*)d_in[0];
  const int*   wbnd     = (const int*)d_in[1];
  const int*   wlen     = (const int*)d_in[2];
  const float* w1  = (const float*)d_in[3];
  const float* b1  = (const float*)d_in[4];
  const float* w2  = (const float*)d_in[5];
  const float* b2  = (const float*)d_in[6];
  const float* w3  = (const float*)d_in[7];
  const float* b3  = (const float*)d_in[8];
  const float* cw1 = (const float*)d_in[9];
  const float* cb1 = (const float*)d_in[10];
  const float* cw2 = (const float*)d_in[11];
  const float* cb2 = (const float*)d_in[12];
  const float* lw  = (const float*)d_in[13];
  const float* lb  = (const float*)d_in[14];
  const float* cw3 = (const float*)d_in[15];
  const float* cb3 = (const float*)d_in[16];
  float* out = (float*)d_out;

  char* ws = (char*)d_ws;
  ushort* ft   = (ushort*)(ws + 0);           // 16,777,216 B  [b][t][128]
  ushort* x1t  = (ushort*)(ws + 16777216);
  ushort* x2t  = (ushort*)(ws + 33554432);
  ushort* embt = (ushort*)(ws + 0);           // over ft (dead after layer1)
  ushort* y1t  = (ushort*)(ws + 16777216);    // 67,108,864 B (x1t/x2t dead)
  float*  z    = (float*)(ws + 83886080);     // 1,048,576 B
  ushort* Wb1  = (ushort*)(ws + 84934656);    // 102,400 B
  ushort* Wb2  = (ushort*)(ws + 85037056);    // 163,840 B
  ushort* Wb3  = (ushort*)(ws + 85200896);    // 163,840 B
  ushort* Wc1  = (ushort*)(ws + 85364736);    // 819,200 B
  ushort* Wc2  = (ushort*)(ws + 86183936);    // 819,200 B
  ushort* zp   = (ushort*)(ws + 87003136);    // 4,096 B zero page
  float*  T2   = (float*)(ws + 87007232);     // 7,680 B (640*3 f32)
  float*  Ls   = (float*)(ws + 87014912);     // 20 B

  const int DYN = 16896 * 2;                  // 33,792 B dynamic LDS (1 slab)
  hipFuncSetAttribute((const void*)conv2d1_mfma,
                      hipFuncAttributeMaxDynamicSharedMemorySize, DYN);
  hipFuncSetAttribute((const void*)conv2d2_mfma,
                      hipFuncAttributeMaxDynamicSharedMemorySize, DYN);

  prep_all<<<5068, 256, 0, stream>>>(features, w1, w2, w3, cw1, cw2, cb1, lw,
                                     ft, Wb1, Wb2, Wb3, Wc1, Wc2, T2, Ls, zp);
  conv1d_mfma<5, 1><<<1024, 256, 0, stream>>>(ft, Wb1, b1, x1t, zp);
  conv1d_mfma<8, 1><<<1024, 256, 0, stream>>>(x1t, Wb2, b2, x2t, zp);
  conv1d_mfma<8, 0><<<1024, 256, 0, stream>>>(x2t, Wb3, b3, embt, zp);
  conv2d1_mfma<<<BB * WW, 256, DYN, stream>>>(embt, wbnd, wlen, Wc1, cb1, y1t, zp);
  conv2d2_mfma<<<BB * WW, 256, DYN, stream>>>(y1t, wbnd, wlen, Wc2, cb2, lw, lb,
                                              T2, Ls, z, zp);
  final_k<<<BB, 256, 0, stream>>>(z, cw3, cb3, out);
}

// Round 11
// 331.135 us; speedup vs baseline: 1.5623x; 1.0316x over previous
//
#include <hip/hip_runtime.h>
#include <hip/hip_bf16.h>

#define BB 32
#define TT 2048
#define MELS 80
#define HH 128
#define WW 64
#define DD 128

using bf16x8 = __attribute__((ext_vector_type(8))) short;
using f32x16 = __attribute__((ext_vector_type(16))) float;
using u16x4  = __attribute__((ext_vector_type(4))) ushort;

#define MFMA(av, bv, acc) acc = __builtin_amdgcn_mfma_f32_32x32x16_bf16(av, bv, acc, 0, 0, 0)

__device__ __forceinline__ ushort bf16b(float f) {
  __hip_bfloat16 h = __float2bfloat16(f);
  return *(ushort*)&h;
}

// async global->LDS 16B DMA (linear LDS dest; swizzle goes on the SOURCE)
__device__ __forceinline__ void g2l16(const ushort* g, ushort* l) {
  __builtin_amdgcn_global_load_lds((const __attribute__((address_space(1))) void*)g,
                                   (__attribute__((address_space(3))) void*)l, 16, 0, 0);
}

// Epilogue helper: scatter one 32x32 C-tile into LDS s_y[col][row] (bf16,
// 4-bit XOR swizzle on 16B blocks) with bias+optional relu.
__device__ __forceinline__ void dump_tile(const f32x16& a, int tl, int mb, int half,
                                          const float* __restrict__ bias, bool relu,
                                          ushort* s_y) {
  #pragma unroll
  for (int q = 0; q < 4; ++q) {
    int ho0 = mb + 8 * q + 4 * half;
    u16x4 p;
    #pragma unroll
    for (int j = 0; j < 4; ++j) {
      float v = a[q * 4 + j] + bias[ho0 + j];
      if (relu) v = fmaxf(v, 0.f);
      p[j] = bf16b(v);
    }
    *(u16x4*)&s_y[tl * 128 + (((ho0 >> 3) ^ (tl & 15)) << 3) + (ho0 & 7)] = p;
  }
}

// ---------------- fused prep: tr_feat + 3x repack1d + 2x repack2d + T2/Ls + zp/cvp
__global__ __launch_bounds__(256) void prep_all(
    const float* __restrict__ features,
    const float* __restrict__ w1, const float* __restrict__ w2,
    const float* __restrict__ w3, const float* __restrict__ cw1,
    const float* __restrict__ cw2, const float* __restrict__ cb1,
    const float* __restrict__ lw,
    ushort* __restrict__ ft, ushort* __restrict__ Wb1, ushort* __restrict__ Wb2,
    ushort* __restrict__ Wb3, ushort* __restrict__ Wc1, ushort* __restrict__ Wc2,
    float* __restrict__ T2, float* __restrict__ Ls, ushort* __restrict__ zp,
    ushort* __restrict__ cvp) {
  __shared__ float s[MELS][65];
  const int bb = blockIdx.x, tid = threadIdx.x;
  if (bb < 1024) {
    // features [b][80][t] f32 -> ft [b][t][128] bf16 (c>=80 -> 0)
    const int b = bb >> 5, t0 = (bb & 31) * 64;
    for (int i = tid; i < MELS * 64; i += 256) {
      int c = i >> 6, t = i & 63;
      s[c][t] = features[(b * MELS + c) * TT + t0 + t];
    }
    __syncthreads();
    for (int i = tid; i < 64 * 128; i += 256) {
      int t = i >> 7, c = i & 127;
      float v = (c < MELS) ? s[c][t] : 0.f;
      ft[(b * TT + t0 + t) * 128 + c] = bf16b(v);
    }
  } else if (bb < 1864) {
    // repack1d: w[m][c][kw] -> Wb[kw][ss][half][m][e], c = ss*16+half*8+e
    int rel, NSS, C; const float* w; ushort* Wb;
    if (bb < 1224)      { rel = bb - 1024; NSS = 5; C = MELS; w = w1; Wb = Wb1; }
    else if (bb < 1544) { rel = bb - 1224; NSS = 8; C = HH;   w = w2; Wb = Wb2; }
    else                { rel = bb - 1544; NSS = 8; C = HH;   w = w3; Wb = Wb3; }
    int i = rel * 256 + tid;
    int e = i & 7, m = (i >> 3) & 127, half = (i >> 10) & 1;
    int r = i >> 11;
    int ss = r % NSS, kw = r / NSS;
    int c = ss * 16 + half * 8 + e;
    Wb[i] = bf16b(w[(m * C + c) * 5 + kw]);
  } else if (bb < 5064) {
    // repack2d: cw[m][hi][kw][kd] -> Wc[kd][kw][ss][half][m][e]
    int rel; const float* cw; ushort* Wc;
    if (bb < 3464) { rel = bb - 1864; cw = cw1; Wc = Wc1; }
    else           { rel = bb - 3464; cw = cw2; Wc = Wc2; }
    int i = rel * 256 + tid;
    int e = i & 7, m = (i >> 3) & 127, half = (i >> 10) & 1, ss = (i >> 11) & 7;
    int r = i >> 14;
    int kw = r % 5, kd = r / 5;
    int hi = ss * 16 + half * 8 + e;
    Wc[i] = bf16b(cw[((m * HH + hi) * 5 + kw) * 5 + kd]);
  } else if (bb < 5067) {
    // T2[(ho*5+kw)*3+v]: v=0 kd0..4; v=1 kd0..3; v=2 kd0..2.  Ls[c]=sum_{d>=32c} lw
    int i = (bb - 5064) * 256 + tid;
    if (i < 640) {
      int ho = i / 5, kw = i - ho * 5;
      float sA = 0.f, sB = 0.f, sC = 0.f;
      for (int hi = 0; hi < HH; ++hi) {
        float yc = fmaxf(cb1[hi], 0.f);
        const float* p = cw2 + ((ho * HH + hi) * 5 + kw) * 5;
        float c012 = p[0] + p[1] + p[2];
        sC += c012 * yc;
        sB += (c012 + p[3]) * yc;
        sA += (c012 + p[3] + p[4]) * yc;
      }
      T2[i * 3 + 0] = sA; T2[i * 3 + 1] = sB; T2[i * 3 + 2] = sC;
    } else if (i < 645) {
      int c = i - 640;
      float sv = 0.f;
      for (int d = c * 32; d < 128; ++d) sv += lw[d];
      Ls[c] = sv;   // Ls[4] = 0
    }
  } else {
    *(bf16x8*)(zp + tid * 8) = (short)0;   // 4096 B zero page
    if (tid < 128) cvp[tid] = bf16b(fmaxf(cb1[tid], 0.f));  // const y1 row
  }
}

// ---------------- conv1d via MFMA: xt[b][t][128] -> yt[b][t][128] ----------
// t-tile 64, grid 1024, 17.4 KB slab -> 4 blocks/CU. Early-exit blocks whose
// output is never consumed: layer out only needed on [lo-D, hi+D),
// lo = bnds[0], hi = end of last valid word (D = 4/2/0 for layers 1/2/3).
template<int NSS, int RELU, int D>
__global__ __launch_bounds__(256) void conv1d_mfma(
    const ushort* __restrict__ xt, const ushort* __restrict__ Wb,
    const float* __restrict__ bias, ushort* __restrict__ yt,
    const ushort* __restrict__ zp, const int* __restrict__ wb,
    const int* __restrict__ wlen) {
  __shared__ __align__(16) ushort s_x[1088 * 8];
  const int bid = blockIdx.x;
  const int nid = (bid & 7) * 128 + (bid >> 3);   // XCD-chunked (1024 % 8 == 0)
  const int b = nid >> 5;
  const int t0 = (nid & 31) << 6;
  const int wlb = wlen[b];
  const int lo = wb[b * 128];
  const int hi = wb[b * 128 + 64 + wlb - 1];
  if (t0 >= hi + D || t0 + 64 <= lo - D) return;   // output never consumed
  const int tid = threadIdx.x;
  const int lane = tid & 63, wv = tid >> 6;
  const int l31 = lane & 31, half = lane >> 5;
  const int m_w = (wv >> 1) * 64, n32 = (wv & 1) * 32;

  #pragma unroll
  for (int it = 0; it < 5; ++it) {
    int slot = it * 256 + tid;
    if (slot < 1088) {
      int row = slot >> 4, bsw = (slot & 15) ^ (row & 15);
      int t = t0 + row - 2;
      const ushort* src = ((unsigned)t < TT)
          ? xt + (((size_t)(b * TT + t)) << 7) + bsw * 8 : zp;
      g2l16(src, s_x + slot * 8);
    }
  }
  __syncthreads();

  f32x16 a0 = 0.f, a1 = 0.f;
  const bf16x8* Ap = (const bf16x8*)Wb;
  constexpr int G = 5 * NSS;
  #pragma unroll
  for (int g = 0; g < G; ++g) {
    const int kw = g / NSS, ss = g % NSS;
    int r0 = n32 + l31 + kw;
    int blk = ss * 2 + half;
    bf16x8 bv = *(const bf16x8*)&s_x[r0 * 128 + ((blk ^ (r0 & 15)) << 3)];
    int ai = ((kw * NSS + ss) * 2 + half) * 128 + m_w + l31;
    MFMA(Ap[ai],      bv, a0);
    MFMA(Ap[ai + 32], bv, a1);
  }
  __syncthreads();
  dump_tile(a0, n32 + l31, m_w,      half, bias, RELU != 0, s_x);
  dump_tile(a1, n32 + l31, m_w + 32, half, bias, RELU != 0, s_x);
  __syncthreads();
  #pragma unroll
  for (int it = 0; it < 4; ++it) {
    int i = it * 256 + tid;        // 64 t x 16 blk = 1024 slots
    int tl = i >> 4, blk = i & 15;
    bf16x8 v = *(const bf16x8*)&s_x[tl * 128 + ((blk ^ (tl & 15)) << 3)];
    *(bf16x8*)(yt + (((size_t)(b * TT + t0 + tl)) << 7) + blk * 8) = v;
  }
}

// ---- per-wave compute of one kw slab: M64 x N64, A-regs double-buffered ----
// NB = active 64-wide n-blocks for this wave (2 = both, 1 = bv0 only).
#define COMPUTE2D(KW, BUF, NB)                                                 \
  {                                                                            \
    bf16x8 ar[2][8];                                                           \
    _Pragma("unroll")                                                          \
    for (int j = 0; j < 8; ++j)                                                \
      ar[0][j] = Ap[(((0 * 5 + (KW)) * 8 + (j >> 1)) * 2 + half) * 128 +       \
                    m_w + l31 + (j & 1) * 32];                                 \
    __builtin_amdgcn_s_setprio(1);                                             \
    _Pragma("unroll")                                                          \
    for (int g = 0; g < 10; ++g) {                                             \
      int kd = g >> 1, sh = (g & 1) * 4;                                       \
      if (g < 9) {                                                             \
        int kd2 = (g + 1) >> 1, sh2 = ((g + 1) & 1) * 4;                       \
        _Pragma("unroll")                                                      \
        for (int j = 0; j < 8; ++j)                                            \
          ar[(g + 1) & 1][j] = Ap[(((kd2 * 5 + (KW)) * 8 + sh2 + (j >> 1)) * 2 \
                                   + half) * 128 + m_w + l31 + (j & 1) * 32];  \
      }                                                                        \
      _Pragma("unroll")                                                        \
      for (int s2 = 0; s2 < 4; ++s2) {                                         \
        int ss = sh + s2;                                                      \
        int r0 = n_w + l31 + kd;                                               \
        int blk = ss * 2 + half;                                               \
        bf16x8 bv0 = *(const bf16x8*)&(BUF)[r0 * 128 + ((blk ^ (r0 & 15)) << 3)]; \
        MFMA(ar[g & 1][s2 * 2],     bv0, a00);                                 \
        MFMA(ar[g & 1][s2 * 2 + 1], bv0, a10);                                 \
        if ((NB) > 1) {                                                        \
          int r1 = r0 + 32;                                                    \
          bf16x8 bv1 = *(const bf16x8*)&(BUF)[r1 * 128 + ((blk ^ (r1 & 15)) << 3)]; \
          MFMA(ar[g & 1][s2 * 2],     bv1, a01);                               \
          MFMA(ar[g & 1][s2 * 2 + 1], bv1, a11);                               \
        }                                                                      \
      }                                                                        \
    }                                                                          \
    __builtin_amdgcn_s_setprio(0);                                             \
  }

// ---------------- fused gather + conv2d #1 (MFMA) -> y1t[b][w][d][hi] ------
// Stores ONLY d < NT1*32; rows beyond are the global const row (cvp), which
// conv2d2 sources directly.
__global__ __launch_bounds__(256, 4) void conv2d1_mfma(
    const ushort* __restrict__ embt, const int* __restrict__ wb,
    const int* __restrict__ wlen, const ushort* __restrict__ Wc,
    const float* __restrict__ cb, ushort* __restrict__ y1t,
    const ushort* __restrict__ zp) {
  extern __shared__ __align__(16) ushort smem[];   // 16896 ushorts
  const int bid = blockIdx.x;
  const int nid = (bid & 7) * 256 + (bid >> 3);    // XCD-chunked (2048 % 8 == 0)
  const int b = nid >> 6, w = nid & 63;
  const int tid = threadIdx.x;
  const int lane = tid & 63, wv = tid >> 6;
  const int l31 = lane & 31, half = lane >> 5;
  const int m_w = (wv >> 1) * 64, n_w = (wv & 1) * 64;

  int stv[5], duv[5];
  const int wl = wlen[b];
  #pragma unroll
  for (int i = 0; i < 5; ++i) {
    int wq = w + i - 2;
    bool ok = ((unsigned)wq < WW) && (wq < wl);
    int st = ok ? wb[b * 128 + wq] : 0;
    int en = ok ? wb[b * 128 + 64 + wq] : 0;
    stv[i] = st;
    duv[i] = ok ? min(en - st, 128) : 0;
  }
  // y1[w,d] is exactly relu(cb1) (const per channel) for d >= max5(dur)+2
  int dcap = 0;
  #pragma unroll
  for (int i = 0; i < 5; ++i) dcap = max(dcap, duv[i]);
  const int NT1 = min(4, max(1, (dcap + 2 + 31) >> 5));
  const int rstage = min(132, NT1 * 32 + 4);
  const int t0a = n_w >> 5;
  const bool act0 = t0a < NT1, act1 = t0a + 1 < NT1;

#define STAGE1(KW)                                                             \
  {                                                                            \
    const int st_ = stv[KW], du_ = duv[KW];                                    \
    if (du_ > 0) {                                                             \
      const int rs_ = min(rstage, (((du_ + 33) >> 5) << 5) + 4);               \
      _Pragma("unroll")                                                        \
      for (int it = 0; it < 9; ++it) {                                         \
        int slot = it * 256 + tid;                                             \
        if (slot < 2112) {                                                     \
          int row = slot >> 4;                                                 \
          if (row < rs_) {                                                     \
            int bsw = (slot & 15) ^ (row & 15);                                \
            int dq = row - 2;                                                  \
            const ushort* src = ((unsigned)dq < (unsigned)du_)                 \
                ? embt + (((size_t)(b * TT + st_ + dq)) << 7) + bsw * 8 : zp;  \
            g2l16(src, smem + slot * 8);                                       \
          }                                                                    \
        }                                                                      \
      }                                                                        \
    }                                                                          \
  }

  f32x16 a00 = 0.f, a01 = 0.f, a10 = 0.f, a11 = 0.f;
  const bf16x8* Ap = (const bf16x8*)Wc;

  STAGE1(0);
  __syncthreads();
  #pragma unroll
  for (int kw = 0; kw < 5; ++kw) {
    const int du = duv[kw];
    const bool a1k = act1 && (du + 2 > n_w + 32);
    const bool a0k = act0 && (du > 0) && (du + 2 > n_w);
    if (a1k)      { COMPUTE2D(kw, smem, 2); }
    else if (a0k) { COMPUTE2D(kw, smem, 1); }
    __syncthreads();
    if (kw < 4) {
      switch (kw + 1) {     // compile-time under unroll
        case 1: STAGE1(1); break;
        case 2: STAGE1(2); break;
        case 3: STAGE1(3); break;
        case 4: STAGE1(4); break;
      }
      __syncthreads();
    }
  }
#undef STAGE1

  if (act0) {
    dump_tile(a00, n_w + l31, m_w,      half, cb, true, smem);
    dump_tile(a10, n_w + l31, m_w + 32, half, cb, true, smem);
  }
  if (act1) {
    dump_tile(a01, n_w + 32 + l31, m_w,      half, cb, true, smem);
    dump_tile(a11, n_w + 32 + l31, m_w + 32, half, cb, true, smem);
  }
  __syncthreads();
  #pragma unroll
  for (int it = 0; it < 8; ++it) {
    int i = it * 256 + tid;
    int d = i >> 4, blk = i & 15;
    if (d < NT1 * 32) {
      bf16x8 v = *(const bf16x8*)&smem[d * 128 + ((blk ^ (d & 15)) << 3)];
      *(bf16x8*)(y1t + (((size_t)(b * WW + w) * DD + d) << 7) + blk * 8) = v;
    }
  }
}

// ---------------- conv2d #2 (MFMA) + relu + einsum(lw) + relu -> z f32 -----
// Stages y1t only for rows the producer wrote (dq < NT1(wq)*32); beyond that
// the value is the global const row cvp; OOB rows are zero (zp).
__global__ __launch_bounds__(256, 4) void conv2d2_mfma(
    const ushort* __restrict__ y1t, const int* __restrict__ wb,
    const int* __restrict__ wlen, const ushort* __restrict__ Wc,
    const float* __restrict__ cb, const float* __restrict__ lw,
    const float* __restrict__ lb, const float* __restrict__ T2,
    const float* __restrict__ Ls, float* __restrict__ z,
    const ushort* __restrict__ zp, const ushort* __restrict__ cvp) {
  extern __shared__ __align__(16) ushort smem[];   // 16896 ushorts
  const int bid = blockIdx.x;
  const int nid = (bid & 7) * 256 + (bid >> 3);
  const int b = nid >> 6, w = nid & 63;
  const int tid = threadIdx.x;
  const int lane = tid & 63, wv = tid >> 6;
  const int l31 = lane & 31, half = lane >> 5;
  const int m_w = (wv >> 1) * 64, n_w = (wv & 1) * 64;

  // y2[w,d] is analytically const for d >= max over w±4 (9 words) of dur + 4
  int duq[9];
  int dmax = 0;
  const int wl = wlen[b];
  #pragma unroll
  for (int i = 0; i < 9; ++i) {
    int wq = w + i - 4;
    int du = 0;
    if ((unsigned)wq < WW && wq < wl)
      du = min(wb[b * 128 + 64 + wq] - wb[b * 128 + wq], 128);
    duq[i] = du;
    dmax = max(dmax, du);
  }
  const int NT2 = min(4, max(1, (dmax + 4 + 31) >> 5));
  const int rstage = min(132, NT2 * 32 + 4);
  const int t0a = n_w >> 5;
  const bool act0 = t0a < NT2, act1 = t0a + 1 < NT2;

#define STAGE2(KW)                                                             \
  {                                                                            \
    const int wq_ = w + (KW) - 2;                                              \
    if ((unsigned)wq_ < WW) {                                                  \
      int dc_ = 0;                                                             \
      _Pragma("unroll")                                                        \
      for (int m5 = 0; m5 < 5; ++m5) dc_ = max(dc_, duq[(KW) + m5]);           \
      const int lim_ = min(4, max(1, (dc_ + 33) >> 5)) << 5;  /* NT1(wq)*32 */ \
      _Pragma("unroll")                                                        \
      for (int it = 0; it < 9; ++it) {                                         \
        int slot = it * 256 + tid;                                             \
        if (slot < 2112) {                                                     \
          int row = slot >> 4;                                                 \
          if (row < rstage) {                                                  \
            int bsw = (slot & 15) ^ (row & 15);                                \
            int dq = row - 2;                                                  \
            const ushort* src;                                                 \
            if ((unsigned)dq < (unsigned)lim_)                                 \
              src = y1t + (((size_t)(b * WW + wq_) * DD + dq) << 7) + bsw * 8; \
            else if ((unsigned)dq < (unsigned)DD)                              \
              src = cvp + bsw * 8;                                             \
            else                                                               \
              src = zp;                                                        \
            g2l16(src, smem + slot * 8);                                       \
          }                                                                    \
        }                                                                      \
      }                                                                        \
    }                                                                          \
  }

  f32x16 a00 = 0.f, a01 = 0.f, a10 = 0.f, a11 = 0.f;
  const bf16x8* Ap = (const bf16x8*)Wc;

  STAGE2(0);
  __syncthreads();
  #pragma unroll
  for (int kw = 0; kw < 5; ++kw) {
    const bool kok = (unsigned)(w + kw - 2) < WW;   // OOB slab is all-zero: skip
    if (kok && act1)      { COMPUTE2D(kw, smem, 2); }
    else if (kok && act0) { COMPUTE2D(kw, smem, 1); }
    __syncthreads();
    if (kw < 4) {
      switch (kw + 1) {
        case 1: STAGE2(1); break;
        case 2: STAGE2(2); break;
        case 3: STAGE2(3); break;
        case 4: STAGE2(4); break;
      }
      __syncthreads();
    }
  }
#undef STAGE2

  // epilogue: relu(acc+cb)*lw over computed d, reduce; const tail analytic
  float* s_red = (float*)smem;            // [128][2]
  const float lw0 = lw[n_w + l31], lw1 = lw[n_w + 32 + l31];
  #pragma unroll
  for (int r = 0; r < 16; ++r) {
    int rowoff = (r & 3) + 8 * (r >> 2) + 4 * half;
    {
      int ho = m_w + rowoff;
      float c = cb[ho];
      float v = (act0 ? fmaxf(a00[r] + c, 0.f) * lw0 : 0.f)
              + (act1 ? fmaxf(a01[r] + c, 0.f) * lw1 : 0.f);
      v += __shfl_xor(v, 1); v += __shfl_xor(v, 2); v += __shfl_xor(v, 4);
      v += __shfl_xor(v, 8); v += __shfl_xor(v, 16);
      if (l31 == 0) s_red[ho * 2 + (wv & 1)] = v;
    }
    {
      int ho = m_w + 32 + rowoff;
      float c = cb[ho];
      float v = (act0 ? fmaxf(a10[r] + c, 0.f) * lw0 : 0.f)
              + (act1 ? fmaxf(a11[r] + c, 0.f) * lw1 : 0.f);
      v += __shfl_xor(v, 1); v += __shfl_xor(v, 2); v += __shfl_xor(v, 4);
      v += __shfl_xor(v, 8); v += __shfl_xor(v, 16);
      if (l31 == 0) s_red[ho * 2 + (wv & 1)] = v;
    }
  }
  __syncthreads();
  if (tid < HH) {
    int ho = tid;
    float hiv = 0.f;
    if (NT2 < 4) {
      float ccA = 0.f, ccB = 0.f, ccC = 0.f;
      #pragma unroll
      for (int kw = 0; kw < 5; ++kw) {
        int wq = w + kw - 2;
        if ((unsigned)wq < WW) {
          ccA += T2[(ho * 5 + kw) * 3 + 0];
          ccB += T2[(ho * 5 + kw) * 3 + 1];
          ccC += T2[(ho * 5 + kw) * 3 + 2];
        }
      }
      float c = cb[ho];
      float l126 = lw[126], l127 = lw[127];
      hiv = fmaxf(ccA + c, 0.f) * (Ls[NT2] - l126 - l127)
          + fmaxf(ccB + c, 0.f) * l126
          + fmaxf(ccC + c, 0.f) * l127;
    }
    float zz = fmaxf(s_red[ho * 2] + s_red[ho * 2 + 1] + hiv + lb[0], 0.f);
    z[(b * HH + ho) * WW + w] = zz;
  }
}

// ---------------- final conv2d (1 out channel, D-dim=1 -> only kd=2) -------
__global__ __launch_bounds__(256) void final_k(const float* __restrict__ z,
        const float* __restrict__ cw3, const float* __restrict__ cb3,
        float* __restrict__ out) {
  __shared__ float sred[4][64];
  const int b = blockIdx.x;
  const int tid = threadIdx.x;
  const int w = tid & 63, g = tid >> 6;
  float acc = 0.f;
  for (int hi = g * 32; hi < g * 32 + 32; ++hi) {
    const float* zp_ = z + (b * HH + hi) * WW;
    const float* cp = cw3 + hi * 25 + 2;
    #pragma unroll
    for (int kw = 0; kw < 5; ++kw) {
      int ww = w + kw - 2;
      if ((unsigned)ww < WW) acc += cp[kw * 5] * zp_[ww];
    }
  }
  sred[g][w] = acc;
  __syncthreads();
  if (tid < 64)
    out[b * WW + w] = cb3[0] + sred[0][w] + sred[1][w] + sred[2][w] + sred[3][w];
}

extern "C" void kernel_launch(void* const* d_in, const int* in_sizes, int n_in,
                              void* d_out, int out_size, void* d_ws, size_t ws_size,
                              hipStream_t stream) {
  const float* features = (const float*)d_in[0];
  const int*   wbnd     = (const int*)d_in[1];
  const int*   wlen     = (const int*)d_in[2];
  const float* w1  = (const float*)d_in[3];
  const float* b1  = (const float*)d_in[4];
  const float* w2  = (const float*)d_in[5];
  const float* b2  = (const float*)d_in[6];
  const float* w3  = (const float*)d_in[7];
  const float* b3  = (const float*)d_in[8];
  const float* cw1 = (const float*)d_in[9];
  const float* cb1 = (const float*)d_in[10];
  const float* cw2 = (const float*)d_in[11];
  const float* cb2 = (const float*)d_in[12];
  const float* lw  = (const float*)d_in[13];
  const float* lb  = (const float*)d_in[14];
  const float* cw3 = (const float*)d_in[15];
  const float* cb3 = (const float*)d_in[16];
  float* out = (float*)d_out;

  char* ws = (char*)d_ws;
  ushort* ft   = (ushort*)(ws + 0);           // 16,777,216 B  [b][t][128]
  ushort* x1t  = (ushort*)(ws + 16777216);
  ushort* x2t  = (ushort*)(ws + 33554432);
  ushort* embt = (ushort*)(ws + 0);           // over ft (dead after layer1)
  ushort* y1t  = (ushort*)(ws + 16777216);    // 67,108,864 B (x1t/x2t dead)
  float*  z    = (float*)(ws + 83886080);     // 1,048,576 B
  ushort* Wb1  = (ushort*)(ws + 84934656);    // 102,400 B
  ushort* Wb2  = (ushort*)(ws + 85037056);    // 163,840 B
  ushort* Wb3  = (ushort*)(ws + 85200896);    // 163,840 B
  ushort* Wc1  = (ushort*)(ws + 85364736);    // 819,200 B
  ushort* Wc2  = (ushort*)(ws + 86183936);    // 819,200 B
  ushort* zp   = (ushort*)(ws + 87003136);    // 4,096 B zero page
  float*  T2   = (float*)(ws + 87007232);     // 7,680 B (640*3 f32)
  float*  Ls   = (float*)(ws + 87014912);     // 20 B
  ushort* cvp  = (ushort*)(ws + 87015424);    // 256 B const y1 row

  const int DYN = 16896 * 2;                  // 33,792 B dynamic LDS (1 slab)
  hipFuncSetAttribute((const void*)conv2d1_mfma,
                      hipFuncAttributeMaxDynamicSharedMemorySize, DYN);
  hipFuncSetAttribute((const void*)conv2d2_mfma,
                      hipFuncAttributeMaxDynamicSharedMemorySize, DYN);

  prep_all<<<5068, 256, 0, stream>>>(features, w1, w2, w3, cw1, cw2, cb1, lw,
                                     ft, Wb1, Wb2, Wb3, Wc1, Wc2, T2, Ls, zp, cvp);
  conv1d_mfma<5, 1, 4><<<1024, 256, 0, stream>>>(ft, Wb1, b1, x1t, zp, wbnd, wlen);
  conv1d_mfma<8, 1, 2><<<1024, 256, 0, stream>>>(x1t, Wb2, b2, x2t, zp, wbnd, wlen);
  conv1d_mfma<8, 0, 0><<<1024, 256, 0, stream>>>(x2t, Wb3, b3, embt, zp, wbnd, wlen);
  conv2d1_mfma<<<BB * WW, 256, DYN, stream>>>(embt, wbnd, wlen, Wc1, cb1, y1t, zp);
  conv2d2_mfma<<<BB * WW, 256, DYN, stream>>>(y1t, wbnd, wlen, Wc2, cb2, lw, lb,
                                              T2, Ls, z, zp, cvp);
  final_k<<<BB, 256, 0, stream>>>(z, cw3, cb3, out);
}